// Round 5
// baseline (1847.419 us; speedup 1.0000x reference)
//
#include <hip/hip_runtime.h>

#define NN 5000
#define EE 10000
#define F_IN 16
#define F_EDGE 4
#define H 96
#define EHD 16
#define HID3 32
#define T_CHEB 5
#define L_LAYERS 10
#define C_OUT 3
#define LN_EPSF 1e-5f
#define MWM 576   // 4 attr mats + const mat + root mat
#define PW 480    // P stores the 5 edge-relevant col-blocks
#define MD 32     // ELL max in-degree
#define GRID 256  // one block per CU: co-residency guaranteed (1 block/CU)
#define BLK 512   // 8 waves/block = 2 waves/SIMD
#define NT (GRID * BLK)
#define BM 128
#define NB_TILES 40          // ceil(5000/128)
#define NTILES (NB_TILES * 6)

struct KArgs {
    const float* x; const int* row; const int* col; const float* eattr;
    const float* cheb_w; const float* cheb_b; const float* enc_w; const float* enc_b;
    const float* w1; const float* b1; const float* w2; const float* b2;
    const float* root; const float* conv_b; const float* ln_g; const float* ln_b;
    const float* lin_w; const float* lin_b; float* out;
    unsigned* bar; float* deg; int* cnt;
    float* M; float* TX; int* ell_r; float* ell_m; float4* ell_ea;
    float* hA; float* hB; float* P;
};

// device-scope sense-reversing grid barrier (bar[0]=arrive cnt, bar[1]=generation)
__device__ __forceinline__ void gsync(unsigned* bar) {
    __syncthreads();
    if (threadIdx.x == 0) {
        __threadfence();   // release: drain + make prior writes device-visible
        unsigned g = __hip_atomic_load(bar + 1, __ATOMIC_RELAXED, __HIP_MEMORY_SCOPE_AGENT);
        unsigned arrived = __hip_atomic_fetch_add(bar, 1u, __ATOMIC_ACQ_REL, __HIP_MEMORY_SCOPE_AGENT);
        if (arrived == GRID - 1) {
            __hip_atomic_store(bar, 0u, __ATOMIC_RELAXED, __HIP_MEMORY_SCOPE_AGENT);
            __hip_atomic_fetch_add(bar + 1, 1u, __ATOMIC_RELEASE, __HIP_MEMORY_SCOPE_AGENT);
        } else {
            long spins = 0;
            while (__hip_atomic_load(bar + 1, __ATOMIC_ACQUIRE, __HIP_MEMORY_SCOPE_AGENT) == g) {
                __builtin_amdgcn_s_sleep(2);
                if (++spins > (1L << 26)) break;   // anti-wedge bail
            }
        }
        __threadfence();   // acquire: invalidate stale lines
    }
    __syncthreads();
}

// one Cheb recurrence step: dst[c] = -scale*dinv[c]*sum_in(m*dinv[r]*src[r]) - prev[c]
__device__ __forceinline__ void cheb_step(const KArgs& a, int tid,
                                          const float* __restrict__ src,
                                          const float* __restrict__ prev,
                                          float* __restrict__ dst, float scale) {
    for (int t = tid; t < NN * 4; t += NT) {
        int c = t >> 2, q = t & 3;
        int n = a.cnt[c];
        const int* rp = a.ell_r + c * MD;
        const float* mp = a.ell_m + c * MD;
        float4 acc = make_float4(0.f, 0.f, 0.f, 0.f);
        for (int p = 0; p < n; ++p) {
            float m = mp[p];
            if (m == 0.f) continue;
            int r = rp[p];
            float w = rsqrtf(a.deg[r]);   // deg[r]>=1 when m!=0
            float4 s = *(const float4*)(src + (size_t)r * F_IN + q * 4);
            acc.x = fmaf(w, s.x, acc.x); acc.y = fmaf(w, s.y, acc.y);
            acc.z = fmaf(w, s.z, acc.z); acc.w = fmaf(w, s.w, acc.w);
        }
        float dc = a.deg[c];
        float f = dc > 0.f ? -scale * rsqrtf(dc) : 0.f;
        float4 o = make_float4(f * acc.x, f * acc.y, f * acc.z, f * acc.w);
        if (prev) {
            float4 pv = *(const float4*)(prev + (size_t)c * F_IN + q * 4);
            o.x -= pv.x; o.y -= pv.y; o.z -= pv.z; o.w -= pv.w;
        }
        *(float4*)(dst + (size_t)c * F_IN + q * 4) = o;
    }
}

__global__ __launch_bounds__(BLK, 2) void k_fused(KArgs a) {
    const int tid = blockIdx.x * BLK + (int)threadIdx.x;
    __shared__ float hs[BM][100];   // 51.2 KB, +4 pad
    __shared__ float Mt[16][96];    // 6 KB

    // ======== Phase A: M precompute + ELL setup + masked degree ========
    for (int idx = tid; idx < L_LAYERS * H * H; idx += NT) {
        int i = idx / (H * H);
        int m = idx % (H * H);      // m = h*96 + o
        int h = m / H, o = m % H;
        const float* w2i = a.w2 + (size_t)i * HID3 * H * H;
        const float* w1i = a.w1 + i * EHD * HID3;
        float hcol[HID3];
        #pragma unroll
        for (int k2 = 0; k2 < HID3; ++k2) hcol[k2] = w2i[(size_t)k2 * H * H + m];
        float tcol[EHD];
        #pragma unroll
        for (int ke = 0; ke < EHD; ++ke) {
            float s = 0.f;
            #pragma unroll
            for (int k2 = 0; k2 < HID3; ++k2) s += w1i[ke * HID3 + k2] * hcol[k2];
            tcol[ke] = s;
        }
        float* Mi = a.M + (size_t)i * H * MWM + h * MWM + o;
        #pragma unroll
        for (int f = 0; f < F_EDGE; ++f) {
            float s = 0.f;
            #pragma unroll
            for (int ke = 0; ke < EHD; ++ke) s += a.enc_w[f * EHD + ke] * tcol[ke];
            Mi[f * H] = s;
        }
        float c = a.b2[(size_t)i * H * H + m];
        #pragma unroll
        for (int ke = 0; ke < EHD; ++ke) c += a.enc_b[ke] * tcol[ke];
        #pragma unroll
        for (int k2 = 0; k2 < HID3; ++k2) c += a.b1[i * HID3 + k2] * hcol[k2];
        Mi[4 * H] = c;
        Mi[5 * H] = a.root[(size_t)i * H * H + m];
    }
    for (int e = tid; e < EE; e += NT) {
        int r = a.row[e], c = a.col[e];
        float4 ea = *(const float4*)(a.eattr + e * F_EDGE);
        float m = (ea.x == 0.f && r != c) ? 1.f : 0.f;
        if (m != 0.f) atomicAdd(&a.deg[r], 1.f);   // integer-valued: exact
        int slot = atomicAdd(&a.cnt[c], 1);
        int p = c * MD + slot;
        a.ell_r[p] = r;
        a.ell_m[p] = m;
        a.ell_ea[p] = ea;
    }
    gsync(a.bar);

    // ======== Cheb recurrence (4 steps) ========
    float* T1 = a.TX;
    float* T2 = a.TX + (size_t)NN * F_IN;
    float* T3 = a.TX + (size_t)2 * NN * F_IN;
    float* T4 = a.TX + (size_t)3 * NN * F_IN;
    cheb_step(a, tid, a.x, nullptr, T1, 1.f);  gsync(a.bar);
    cheb_step(a, tid, T1, a.x, T2, 2.f);       gsync(a.bar);
    cheb_step(a, tid, T2, T1, T3, 2.f);        gsync(a.bar);
    cheb_step(a, tid, T3, T2, T4, 2.f);        gsync(a.bar);

    // ======== cheb_out -> hA ========
    for (int idx = tid; idx < NN * H; idx += NT) {
        int n = idx / H, o = idx % H;
        float s = a.cheb_b[o];
        #pragma unroll
        for (int k = 0; k < T_CHEB; ++k) {
            const float* tx = (k == 0) ? a.x + (size_t)n * F_IN
                                       : a.TX + ((size_t)(k - 1) * NN + n) * F_IN;
            const float* w = a.cheb_w + (size_t)k * F_IN * H + o;
            #pragma unroll
            for (int f = 0; f < F_IN; ++f) s = fmaf(tx[f], w[f * H], s);
        }
        a.hA[idx] = s;
    }
    gsync(a.bar);

    // ======== DeepGCN layers ========
    float* hcur = a.hA;
    float* hnext = a.hB;
    for (int li = 0; li < L_LAYERS; ++li) {
        const float* Mi = a.M + (size_t)li * H * MWM;
        const float* cb = a.conv_b + li * H;
        const float* lg = a.ln_g + li * H;
        const float* lb = a.ln_b + li * H;
        const int doLN = li > 0;

        // ---- GEMM phase: 128x96 tiles, LN+ReLU fused ----
        for (int t = blockIdx.x; t < NTILES; t += GRID) {
            int nb = t / 6, jb = t % 6;
            int n0 = nb * BM, j0 = jb * 96;
            {   // stage BMx96 h-tile
                int r = threadIdx.x >> 2, q = threadIdx.x & 3;
                int gn = n0 + r;
                if (gn < NN) {
                    const float* hrow = hcur + (size_t)gn * H + q * 24;
                    #pragma unroll
                    for (int c = 0; c < 24; c += 4)
                        *(float4*)&hs[r][q * 24 + c] = *(const float4*)(hrow + c);
                } else {
                    float4 z = make_float4(0.f, 0.f, 0.f, 0.f);
                    #pragma unroll
                    for (int c = 0; c < 24; c += 4) *(float4*)&hs[r][q * 24 + c] = z;
                }
            }
            __syncthreads();
            if (doLN) {   // LayerNorm+ReLU in LDS, 4 lanes/row, float4 passes
                int r = threadIdx.x >> 2, q = threadIdx.x & 3;
                float4 xv[6];
                #pragma unroll
                for (int c = 0; c < 6; ++c) xv[c] = *(const float4*)&hs[r][q * 24 + c * 4];
                float s = 0.f;
                #pragma unroll
                for (int c = 0; c < 6; ++c) s += xv[c].x + xv[c].y + xv[c].z + xv[c].w;
                s += __shfl_xor(s, 1); s += __shfl_xor(s, 2);
                float mu = s * (1.0f / H);
                float vv = 0.f;
                #pragma unroll
                for (int c = 0; c < 6; ++c) {
                    float dx = xv[c].x - mu, dy = xv[c].y - mu, dz = xv[c].z - mu, dw = xv[c].w - mu;
                    vv += dx * dx + dy * dy + dz * dz + dw * dw;
                }
                vv += __shfl_xor(vv, 1); vv += __shfl_xor(vv, 2);
                float is = rsqrtf(vv * (1.0f / H) + LN_EPSF);
                #pragma unroll
                for (int c = 0; c < 6; ++c) {
                    int cc = q * 24 + c * 4;
                    float4 gv = *(const float4*)(lg + cc);
                    float4 bv = *(const float4*)(lb + cc);
                    float4 ov;
                    ov.x = fmaxf(fmaf((xv[c].x - mu) * is, gv.x, bv.x), 0.f);
                    ov.y = fmaxf(fmaf((xv[c].y - mu) * is, gv.y, bv.y), 0.f);
                    ov.z = fmaxf(fmaf((xv[c].z - mu) * is, gv.z, bv.z), 0.f);
                    ov.w = fmaxf(fmaf((xv[c].w - mu) * is, gv.w, bv.w), 0.f);
                    *(float4*)&hs[r][cc] = ov;
                }
                __syncthreads();
            }
            float acc[4][6] = {};
            const int tx = threadIdx.x & 15, ty = threadIdx.x >> 4;  // ty 0..31
            for (int k0 = 0; k0 < H; k0 += 16) {
                for (int idx = threadIdx.x; idx < 384; idx += BLK) {
                    int kk = idx / 24, jj = (idx % 24) * 4;
                    *(float4*)&Mt[kk][jj] =
                        *(const float4*)(Mi + (size_t)(k0 + kk) * MWM + j0 + jj);
                }
                __syncthreads();
                #pragma unroll
                for (int kk = 0; kk < 16; ++kk) {
                    float aa[4], bb[6];
                    #pragma unroll
                    for (int i2 = 0; i2 < 4; ++i2) aa[i2] = hs[ty * 4 + i2][k0 + kk];
                    #pragma unroll
                    for (int j = 0; j < 6; ++j) bb[j] = Mt[kk][tx * 6 + j];
                    #pragma unroll
                    for (int i2 = 0; i2 < 4; ++i2)
                        #pragma unroll
                        for (int j = 0; j < 6; ++j)
                            acc[i2][j] = fmaf(aa[i2], bb[j], acc[i2][j]);
                }
                __syncthreads();
            }
            if (jb < 5) {
                #pragma unroll
                for (int i2 = 0; i2 < 4; ++i2) {
                    int gn = n0 + ty * 4 + i2;
                    if (gn < NN) {
                        float* pr = a.P + (size_t)gn * PW + j0 + tx * 6;
                        *(float2*)(pr + 0) = make_float2(acc[i2][0], acc[i2][1]);
                        *(float2*)(pr + 2) = make_float2(acc[i2][2], acc[i2][3]);
                        *(float2*)(pr + 4) = make_float2(acc[i2][4], acc[i2][5]);
                    }
                }
            } else {
                #pragma unroll
                for (int i2 = 0; i2 < 4; ++i2) {
                    int gn = n0 + ty * 4 + i2;
                    if (gn < NN) {
                        int ob = tx * 6;
                        float* hp = hnext + (size_t)gn * H + ob;
                        const float* rp = hcur + (size_t)gn * H + ob;
                        #pragma unroll
                        for (int j = 0; j < 6; ++j)
                            hp[j] = acc[i2][j] + cb[ob + j] + (doLN ? rp[j] : 0.f);
                    }
                }
            }
            __syncthreads();
        }
        gsync(a.bar);

        // ---- gather phase (no atomics) ----
        for (int t = tid; t < NN * 12; t += NT) {
            int c = t / 12, o = (t % 12) * 8;
            int n = a.cnt[c];
            const int* rp = a.ell_r + c * MD;
            const float4* eap = a.ell_ea + c * MD;
            float* hp = hnext + (size_t)c * H + o;
            float s[8];
            *(float4*)(s + 0) = *(const float4*)(hp + 0);
            *(float4*)(s + 4) = *(const float4*)(hp + 4);
            for (int p = 0; p < n; ++p) {
                int r = rp[p];
                float4 ea = eap[p];
                const float* pb = a.P + (size_t)r * PW + o;
                float4 c0 = *(const float4*)(pb + 384);
                float4 c1 = *(const float4*)(pb + 388);
                s[0] += c0.x; s[1] += c0.y; s[2] += c0.z; s[3] += c0.w;
                s[4] += c1.x; s[5] += c1.y; s[6] += c1.z; s[7] += c1.w;
                const float cf[4] = {ea.x, ea.y, ea.z, ea.w};
                #pragma unroll
                for (int f = 0; f < 4; ++f) {
                    float4 p0 = *(const float4*)(pb + f * 96);
                    float4 p1 = *(const float4*)(pb + f * 96 + 4);
                    s[0] = fmaf(cf[f], p0.x, s[0]); s[1] = fmaf(cf[f], p0.y, s[1]);
                    s[2] = fmaf(cf[f], p0.z, s[2]); s[3] = fmaf(cf[f], p0.w, s[3]);
                    s[4] = fmaf(cf[f], p1.x, s[4]); s[5] = fmaf(cf[f], p1.y, s[5]);
                    s[6] = fmaf(cf[f], p1.z, s[6]); s[7] = fmaf(cf[f], p1.w, s[7]);
                }
            }
            *(float4*)(hp + 0) = *(const float4*)(s + 0);
            *(float4*)(hp + 4) = *(const float4*)(s + 4);
        }
        gsync(a.bar);

        float* tmp = hcur; hcur = hnext; hnext = tmp;
    }

    // ======== final: LN(params[0]) + relu + linear(96->3) ========
    for (int t = tid; t < NN * 8; t += NT) {
        int n = t >> 3, l8 = t & 7;
        const float* hr = hcur + (size_t)n * H + l8 * 12;
        float xv[12];
        *(float4*)(xv + 0) = *(const float4*)(hr + 0);
        *(float4*)(xv + 4) = *(const float4*)(hr + 4);
        *(float4*)(xv + 8) = *(const float4*)(hr + 8);
        float s = 0.f;
        #pragma unroll
        for (int i = 0; i < 12; ++i) s += xv[i];
        s += __shfl_xor(s, 1); s += __shfl_xor(s, 2); s += __shfl_xor(s, 4);
        float mu = s * (1.0f / H);
        float vv = 0.f;
        #pragma unroll
        for (int i = 0; i < 12; ++i) { float d = xv[i] - mu; vv += d * d; }
        vv += __shfl_xor(vv, 1); vv += __shfl_xor(vv, 2); vv += __shfl_xor(vv, 4);
        float is = rsqrtf(vv * (1.0f / H) + LN_EPSF);
        const float* gp = a.ln_g + l8 * 12;
        const float* bp = a.ln_b + l8 * 12;
        float a0 = 0.f, a1 = 0.f, a2 = 0.f;
        #pragma unroll
        for (int i = 0; i < 12; ++i) {
            float tt = fmaxf(fmaf((xv[i] - mu) * is, gp[i], bp[i]), 0.f);
            int o = l8 * 12 + i;
            a0 = fmaf(tt, a.lin_w[o * C_OUT + 0], a0);
            a1 = fmaf(tt, a.lin_w[o * C_OUT + 1], a1);
            a2 = fmaf(tt, a.lin_w[o * C_OUT + 2], a2);
        }
        a0 += __shfl_xor(a0, 1); a0 += __shfl_xor(a0, 2); a0 += __shfl_xor(a0, 4);
        a1 += __shfl_xor(a1, 1); a1 += __shfl_xor(a1, 2); a1 += __shfl_xor(a1, 4);
        a2 += __shfl_xor(a2, 1); a2 += __shfl_xor(a2, 2); a2 += __shfl_xor(a2, 4);
        if (l8 == 0) {
            a.out[n * C_OUT + 0] = a0 + a.lin_b[0];
            a.out[n * C_OUT + 1] = a1 + a.lin_b[1];
            a.out[n * C_OUT + 2] = a2 + a.lin_b[2];
        }
    }
}

extern "C" void kernel_launch(void* const* d_in, const int* in_sizes, int n_in,
                              void* d_out, int out_size, void* d_ws, size_t ws_size,
                              hipStream_t stream) {
    char* base = (char*)d_ws;
    size_t off = 0;
    auto alloc = [&](size_t nbytes) {
        char* p = base + off;
        off += (nbytes + 255) / 256 * 256;
        return p;
    };

    KArgs a;
    a.x      = (const float*)d_in[0];
    a.row    = (const int*)d_in[1];
    a.col    = (const int*)d_in[1] + EE;
    a.eattr  = (const float*)d_in[2];
    a.cheb_w = (const float*)d_in[3];
    a.cheb_b = (const float*)d_in[4];
    a.enc_w  = (const float*)d_in[5];
    a.enc_b  = (const float*)d_in[6];
    a.w1     = (const float*)d_in[7];
    a.b1     = (const float*)d_in[8];
    a.w2     = (const float*)d_in[9];
    a.b2     = (const float*)d_in[10];
    a.root   = (const float*)d_in[11];
    a.conv_b = (const float*)d_in[12];
    a.ln_g   = (const float*)d_in[13];
    a.ln_b   = (const float*)d_in[14];
    a.lin_w  = (const float*)d_in[15];
    a.lin_b  = (const float*)d_in[16];
    a.out    = (float*)d_out;

    // control region (zeroed each call with ONE memset): bar | deg | cnt
    char* ctl0 = alloc(256);            a.bar = (unsigned*)ctl0;
    a.deg  = (float*)alloc(NN * 4);
    a.cnt  = (int*)  alloc(NN * 4);
    size_t ctl_bytes = (size_t)((char*)a.cnt + ((NN * 4 + 255) / 256 * 256) - ctl0);

    a.M      = (float*)alloc((size_t)L_LAYERS * H * MWM * 4);
    a.TX     = (float*)alloc((size_t)(T_CHEB - 1) * NN * F_IN * 4);
    a.ell_r  = (int*)  alloc((size_t)NN * MD * 4);
    a.ell_m  = (float*)alloc((size_t)NN * MD * 4);
    a.ell_ea = (float4*)alloc((size_t)NN * MD * 16);
    a.hA     = (float*)alloc((size_t)NN * H * 4);
    a.hB     = (float*)alloc((size_t)NN * H * 4);
    a.P      = (float*)alloc((size_t)NN * PW * 4);
    (void)ws_size; (void)n_in; (void)in_sizes; (void)out_size;

    hipMemsetAsync(ctl0, 0, ctl_bytes, stream);
    k_fused<<<dim3(GRID), dim3(BLK), 0, stream>>>(a);
}

// Round 6
// 841.715 us; speedup vs baseline: 2.1948x; 2.1948x over previous
//
#include <hip/hip_runtime.h>

#define NN 5000
#define EE 10000
#define F_IN 16
#define F_EDGE 4
#define H 96
#define EHD 16
#define HID3 32
#define T_CHEB 5
#define L_LAYERS 10
#define C_OUT 3
#define LN_EPSF 1e-5f
#define MWM 576   // 4 attr mats + const mat + root mat
#define PW 480    // P stores the 5 edge-relevant col-blocks
#define MD 32     // ELL max in-degree
#define GRID 256  // one block per CU: co-residency guaranteed
#define BLK 512   // 8 waves/block = 2 waves/SIMD
#define NT (GRID * BLK)
#define BM 128
#define NB_TILES 40          // ceil(5000/128)
#define NTILES (NB_TILES * 6)
#define NBARS 32             // 26 used; counters are single-use (no reset race)

struct KArgs {
    const float* x; const int* row; const int* col; const float* eattr;
    const float* cheb_w; const float* cheb_b; const float* enc_w; const float* enc_b;
    const float* w1; const float* b1; const float* w2; const float* b2;
    const float* root; const float* conv_b; const float* ln_g; const float* ln_b;
    const float* lin_w; const float* lin_b; float* out;
    unsigned* bars; float* deg; int* cnt;
    float* M; float* TX; int* ell_r; float* ell_m; float4* ell_ea;
    float* hA; float* hB; float* P;
};

// grid barrier: monotonic single-use counter per barrier site.
// RELAXED spin (no per-iteration cache maintenance!) + ONE release fence
// before arrival and ONE acquire fence after exit (cross-XCD L2 wb/inv).
__device__ __forceinline__ void gsync(unsigned* bars, int& bi) {
    __syncthreads();
    if (threadIdx.x == 0) {
        unsigned* c = bars + bi;
        __builtin_amdgcn_fence(__ATOMIC_RELEASE, "agent");   // L2 writeback once
        __hip_atomic_fetch_add(c, 1u, __ATOMIC_RELAXED, __HIP_MEMORY_SCOPE_AGENT);
        long spins = 0;
        while (__hip_atomic_load(c, __ATOMIC_RELAXED, __HIP_MEMORY_SCOPE_AGENT) < GRID) {
            __builtin_amdgcn_s_sleep(1);
            if (++spins > (1L << 26)) break;   // anti-wedge bail
        }
        __builtin_amdgcn_fence(__ATOMIC_ACQUIRE, "agent");   // L2 invalidate once
    }
    ++bi;
    __syncthreads();
}

// one Cheb recurrence step: dst[c] = -scale*dinv[c]*sum_in(m*dinv[r]*src[r]) - prev[c]
__device__ __forceinline__ void cheb_step(const KArgs& a, int tid,
                                          const float* __restrict__ src,
                                          const float* __restrict__ prev,
                                          float* __restrict__ dst, float scale) {
    for (int t = tid; t < NN * 4; t += NT) {
        int c = t >> 2, q = t & 3;
        int n = a.cnt[c];
        const int* rp = a.ell_r + c * MD;
        const float* mp = a.ell_m + c * MD;
        float4 acc = make_float4(0.f, 0.f, 0.f, 0.f);
        for (int p = 0; p < n; ++p) {
            float m = mp[p];
            if (m == 0.f) continue;
            int r = rp[p];
            float w = rsqrtf(a.deg[r]);   // deg[r]>=1 when m!=0
            float4 s = *(const float4*)(src + (size_t)r * F_IN + q * 4);
            acc.x = fmaf(w, s.x, acc.x); acc.y = fmaf(w, s.y, acc.y);
            acc.z = fmaf(w, s.z, acc.z); acc.w = fmaf(w, s.w, acc.w);
        }
        float dc = a.deg[c];
        float f = dc > 0.f ? -scale * rsqrtf(dc) : 0.f;
        float4 o = make_float4(f * acc.x, f * acc.y, f * acc.z, f * acc.w);
        if (prev) {
            float4 pv = *(const float4*)(prev + (size_t)c * F_IN + q * 4);
            o.x -= pv.x; o.y -= pv.y; o.z -= pv.z; o.w -= pv.w;
        }
        *(float4*)(dst + (size_t)c * F_IN + q * 4) = o;
    }
}

__global__ __launch_bounds__(BLK, 2) void k_fused(KArgs a) {
    const int tid = blockIdx.x * BLK + (int)threadIdx.x;
    int bi = 0;
    __shared__ float hs[BM][100];   // 51.2 KB, +4 pad
    __shared__ float Mt[16][96];    // 6 KB

    // ======== Phase A: M precompute + ELL setup + masked degree ========
    for (int idx = tid; idx < L_LAYERS * H * H; idx += NT) {
        int i = idx / (H * H);
        int m = idx % (H * H);      // m = h*96 + o
        int h = m / H, o = m % H;
        const float* w2i = a.w2 + (size_t)i * HID3 * H * H;
        const float* w1i = a.w1 + i * EHD * HID3;
        float hcol[HID3];
        #pragma unroll
        for (int k2 = 0; k2 < HID3; ++k2) hcol[k2] = w2i[(size_t)k2 * H * H + m];
        float tcol[EHD];
        #pragma unroll
        for (int ke = 0; ke < EHD; ++ke) {
            float s = 0.f;
            #pragma unroll
            for (int k2 = 0; k2 < HID3; ++k2) s += w1i[ke * HID3 + k2] * hcol[k2];
            tcol[ke] = s;
        }
        float* Mi = a.M + (size_t)i * H * MWM + h * MWM + o;
        #pragma unroll
        for (int f = 0; f < F_EDGE; ++f) {
            float s = 0.f;
            #pragma unroll
            for (int ke = 0; ke < EHD; ++ke) s += a.enc_w[f * EHD + ke] * tcol[ke];
            Mi[f * H] = s;
        }
        float c = a.b2[(size_t)i * H * H + m];
        #pragma unroll
        for (int ke = 0; ke < EHD; ++ke) c += a.enc_b[ke] * tcol[ke];
        #pragma unroll
        for (int k2 = 0; k2 < HID3; ++k2) c += a.b1[i * HID3 + k2] * hcol[k2];
        Mi[4 * H] = c;
        Mi[5 * H] = a.root[(size_t)i * H * H + m];
    }
    for (int e = tid; e < EE; e += NT) {
        int r = a.row[e], c = a.col[e];
        float4 ea = *(const float4*)(a.eattr + e * F_EDGE);
        float m = (ea.x == 0.f && r != c) ? 1.f : 0.f;
        if (m != 0.f) atomicAdd(&a.deg[r], 1.f);   // integer-valued: exact
        int slot = atomicAdd(&a.cnt[c], 1);
        int p = c * MD + slot;
        a.ell_r[p] = r;
        a.ell_m[p] = m;
        a.ell_ea[p] = ea;
    }
    gsync(a.bars, bi);

    // ======== Cheb recurrence (4 steps) ========
    float* T1 = a.TX;
    float* T2 = a.TX + (size_t)NN * F_IN;
    float* T3 = a.TX + (size_t)2 * NN * F_IN;
    float* T4 = a.TX + (size_t)3 * NN * F_IN;
    cheb_step(a, tid, a.x, nullptr, T1, 1.f);  gsync(a.bars, bi);
    cheb_step(a, tid, T1, a.x, T2, 2.f);       gsync(a.bars, bi);
    cheb_step(a, tid, T2, T1, T3, 2.f);        gsync(a.bars, bi);
    cheb_step(a, tid, T3, T2, T4, 2.f);        gsync(a.bars, bi);

    // ======== cheb_out -> hA ========
    for (int idx = tid; idx < NN * H; idx += NT) {
        int n = idx / H, o = idx % H;
        float s = a.cheb_b[o];
        #pragma unroll
        for (int k = 0; k < T_CHEB; ++k) {
            const float* tx = (k == 0) ? a.x + (size_t)n * F_IN
                                       : a.TX + ((size_t)(k - 1) * NN + n) * F_IN;
            const float* w = a.cheb_w + (size_t)k * F_IN * H + o;
            #pragma unroll
            for (int f = 0; f < F_IN; ++f) s = fmaf(tx[f], w[f * H], s);
        }
        a.hA[idx] = s;
    }
    gsync(a.bars, bi);

    // ======== DeepGCN layers ========
    float* hcur = a.hA;
    float* hnext = a.hB;
    for (int li = 0; li < L_LAYERS; ++li) {
        const float* Mi = a.M + (size_t)li * H * MWM;
        const float* cb = a.conv_b + li * H;
        const float* lg = a.ln_g + li * H;
        const float* lb = a.ln_b + li * H;
        const int doLN = li > 0;

        // ---- GEMM phase: 128x96 tiles, LN+ReLU fused ----
        for (int t = blockIdx.x; t < NTILES; t += GRID) {
            int nb = t / 6, jb = t % 6;
            int n0 = nb * BM, j0 = jb * 96;
            {   // stage BMx96 h-tile
                int r = threadIdx.x >> 2, q = threadIdx.x & 3;
                int gn = n0 + r;
                if (gn < NN) {
                    const float* hrow = hcur + (size_t)gn * H + q * 24;
                    #pragma unroll
                    for (int c = 0; c < 24; c += 4)
                        *(float4*)&hs[r][q * 24 + c] = *(const float4*)(hrow + c);
                } else {
                    float4 z = make_float4(0.f, 0.f, 0.f, 0.f);
                    #pragma unroll
                    for (int c = 0; c < 24; c += 4) *(float4*)&hs[r][q * 24 + c] = z;
                }
            }
            __syncthreads();
            if (doLN) {   // LayerNorm+ReLU in LDS, 4 lanes/row, float4 passes
                int r = threadIdx.x >> 2, q = threadIdx.x & 3;
                float4 xv[6];
                #pragma unroll
                for (int c = 0; c < 6; ++c) xv[c] = *(const float4*)&hs[r][q * 24 + c * 4];
                float s = 0.f;
                #pragma unroll
                for (int c = 0; c < 6; ++c) s += xv[c].x + xv[c].y + xv[c].z + xv[c].w;
                s += __shfl_xor(s, 1); s += __shfl_xor(s, 2);
                float mu = s * (1.0f / H);
                float vv = 0.f;
                #pragma unroll
                for (int c = 0; c < 6; ++c) {
                    float dx = xv[c].x - mu, dy = xv[c].y - mu, dz = xv[c].z - mu, dw = xv[c].w - mu;
                    vv += dx * dx + dy * dy + dz * dz + dw * dw;
                }
                vv += __shfl_xor(vv, 1); vv += __shfl_xor(vv, 2);
                float is = rsqrtf(vv * (1.0f / H) + LN_EPSF);
                #pragma unroll
                for (int c = 0; c < 6; ++c) {
                    int cc = q * 24 + c * 4;
                    float4 gv = *(const float4*)(lg + cc);
                    float4 bv = *(const float4*)(lb + cc);
                    float4 ov;
                    ov.x = fmaxf(fmaf((xv[c].x - mu) * is, gv.x, bv.x), 0.f);
                    ov.y = fmaxf(fmaf((xv[c].y - mu) * is, gv.y, bv.y), 0.f);
                    ov.z = fmaxf(fmaf((xv[c].z - mu) * is, gv.z, bv.z), 0.f);
                    ov.w = fmaxf(fmaf((xv[c].w - mu) * is, gv.w, bv.w), 0.f);
                    *(float4*)&hs[r][cc] = ov;
                }
                __syncthreads();
            }
            float acc[4][6] = {};
            const int tx = threadIdx.x & 15, ty = threadIdx.x >> 4;  // ty 0..31
            for (int k0 = 0; k0 < H; k0 += 16) {
                for (int idx = threadIdx.x; idx < 384; idx += BLK) {
                    int kk = idx / 24, jj = (idx % 24) * 4;
                    *(float4*)&Mt[kk][jj] =
                        *(const float4*)(Mi + (size_t)(k0 + kk) * MWM + j0 + jj);
                }
                __syncthreads();
                #pragma unroll
                for (int kk = 0; kk < 16; ++kk) {
                    float aa[4], bb[6];
                    #pragma unroll
                    for (int i2 = 0; i2 < 4; ++i2) aa[i2] = hs[ty * 4 + i2][k0 + kk];
                    #pragma unroll
                    for (int j = 0; j < 6; ++j) bb[j] = Mt[kk][tx * 6 + j];
                    #pragma unroll
                    for (int i2 = 0; i2 < 4; ++i2)
                        #pragma unroll
                        for (int j = 0; j < 6; ++j)
                            acc[i2][j] = fmaf(aa[i2], bb[j], acc[i2][j]);
                }
                __syncthreads();
            }
            if (jb < 5) {
                #pragma unroll
                for (int i2 = 0; i2 < 4; ++i2) {
                    int gn = n0 + ty * 4 + i2;
                    if (gn < NN) {
                        float* pr = a.P + (size_t)gn * PW + j0 + tx * 6;
                        *(float2*)(pr + 0) = make_float2(acc[i2][0], acc[i2][1]);
                        *(float2*)(pr + 2) = make_float2(acc[i2][2], acc[i2][3]);
                        *(float2*)(pr + 4) = make_float2(acc[i2][4], acc[i2][5]);
                    }
                }
            } else {
                #pragma unroll
                for (int i2 = 0; i2 < 4; ++i2) {
                    int gn = n0 + ty * 4 + i2;
                    if (gn < NN) {
                        int ob = tx * 6;
                        float* hp = hnext + (size_t)gn * H + ob;
                        const float* rp = hcur + (size_t)gn * H + ob;
                        #pragma unroll
                        for (int j = 0; j < 6; ++j)
                            hp[j] = acc[i2][j] + cb[ob + j] + (doLN ? rp[j] : 0.f);
                    }
                }
            }
            __syncthreads();
        }
        gsync(a.bars, bi);

        // ---- gather phase (no atomics) ----
        for (int t = tid; t < NN * 12; t += NT) {
            int c = t / 12, o = (t % 12) * 8;
            int n = a.cnt[c];
            const int* rp = a.ell_r + c * MD;
            const float4* eap = a.ell_ea + c * MD;
            float* hp = hnext + (size_t)c * H + o;
            float s[8];
            *(float4*)(s + 0) = *(const float4*)(hp + 0);
            *(float4*)(s + 4) = *(const float4*)(hp + 4);
            for (int p = 0; p < n; ++p) {
                int r = rp[p];
                float4 ea = eap[p];
                const float* pb = a.P + (size_t)r * PW + o;
                float4 c0 = *(const float4*)(pb + 384);
                float4 c1 = *(const float4*)(pb + 388);
                s[0] += c0.x; s[1] += c0.y; s[2] += c0.z; s[3] += c0.w;
                s[4] += c1.x; s[5] += c1.y; s[6] += c1.z; s[7] += c1.w;
                const float cf[4] = {ea.x, ea.y, ea.z, ea.w};
                #pragma unroll
                for (int f = 0; f < 4; ++f) {
                    float4 p0 = *(const float4*)(pb + f * 96);
                    float4 p1 = *(const float4*)(pb + f * 96 + 4);
                    s[0] = fmaf(cf[f], p0.x, s[0]); s[1] = fmaf(cf[f], p0.y, s[1]);
                    s[2] = fmaf(cf[f], p0.z, s[2]); s[3] = fmaf(cf[f], p0.w, s[3]);
                    s[4] = fmaf(cf[f], p1.x, s[4]); s[5] = fmaf(cf[f], p1.y, s[5]);
                    s[6] = fmaf(cf[f], p1.z, s[6]); s[7] = fmaf(cf[f], p1.w, s[7]);
                }
            }
            *(float4*)(hp + 0) = *(const float4*)(s + 0);
            *(float4*)(hp + 4) = *(const float4*)(s + 4);
        }
        gsync(a.bars, bi);

        float* tmp = hcur; hcur = hnext; hnext = tmp;
    }

    // ======== final: LN(params[0]) + relu + linear(96->3) ========
    for (int t = tid; t < NN * 8; t += NT) {
        int n = t >> 3, l8 = t & 7;
        const float* hr = hcur + (size_t)n * H + l8 * 12;
        float xv[12];
        *(float4*)(xv + 0) = *(const float4*)(hr + 0);
        *(float4*)(xv + 4) = *(const float4*)(hr + 4);
        *(float4*)(xv + 8) = *(const float4*)(hr + 8);
        float s = 0.f;
        #pragma unroll
        for (int i = 0; i < 12; ++i) s += xv[i];
        s += __shfl_xor(s, 1); s += __shfl_xor(s, 2); s += __shfl_xor(s, 4);
        float mu = s * (1.0f / H);
        float vv = 0.f;
        #pragma unroll
        for (int i = 0; i < 12; ++i) { float d = xv[i] - mu; vv += d * d; }
        vv += __shfl_xor(vv, 1); vv += __shfl_xor(vv, 2); vv += __shfl_xor(vv, 4);
        float is = rsqrtf(vv * (1.0f / H) + LN_EPSF);
        const float* gp = a.ln_g + l8 * 12;
        const float* bp = a.ln_b + l8 * 12;
        float a0 = 0.f, a1 = 0.f, a2 = 0.f;
        #pragma unroll
        for (int i = 0; i < 12; ++i) {
            float tt = fmaxf(fmaf((xv[i] - mu) * is, gp[i], bp[i]), 0.f);
            int o = l8 * 12 + i;
            a0 = fmaf(tt, a.lin_w[o * C_OUT + 0], a0);
            a1 = fmaf(tt, a.lin_w[o * C_OUT + 1], a1);
            a2 = fmaf(tt, a.lin_w[o * C_OUT + 2], a2);
        }
        a0 += __shfl_xor(a0, 1); a0 += __shfl_xor(a0, 2); a0 += __shfl_xor(a0, 4);
        a1 += __shfl_xor(a1, 1); a1 += __shfl_xor(a1, 2); a1 += __shfl_xor(a1, 4);
        a2 += __shfl_xor(a2, 1); a2 += __shfl_xor(a2, 2); a2 += __shfl_xor(a2, 4);
        if (l8 == 0) {
            a.out[n * C_OUT + 0] = a0 + a.lin_b[0];
            a.out[n * C_OUT + 1] = a1 + a.lin_b[1];
            a.out[n * C_OUT + 2] = a2 + a.lin_b[2];
        }
    }
}

extern "C" void kernel_launch(void* const* d_in, const int* in_sizes, int n_in,
                              void* d_out, int out_size, void* d_ws, size_t ws_size,
                              hipStream_t stream) {
    char* base = (char*)d_ws;
    size_t off = 0;
    auto alloc = [&](size_t nbytes) {
        char* p = base + off;
        off += (nbytes + 255) / 256 * 256;
        return p;
    };

    KArgs a;
    a.x      = (const float*)d_in[0];
    a.row    = (const int*)d_in[1];
    a.col    = (const int*)d_in[1] + EE;
    a.eattr  = (const float*)d_in[2];
    a.cheb_w = (const float*)d_in[3];
    a.cheb_b = (const float*)d_in[4];
    a.enc_w  = (const float*)d_in[5];
    a.enc_b  = (const float*)d_in[6];
    a.w1     = (const float*)d_in[7];
    a.b1     = (const float*)d_in[8];
    a.w2     = (const float*)d_in[9];
    a.b2     = (const float*)d_in[10];
    a.root   = (const float*)d_in[11];
    a.conv_b = (const float*)d_in[12];
    a.ln_g   = (const float*)d_in[13];
    a.ln_b   = (const float*)d_in[14];
    a.lin_w  = (const float*)d_in[15];
    a.lin_b  = (const float*)d_in[16];
    a.out    = (float*)d_out;

    // control region (zeroed each call with ONE memset): bars | deg | cnt
    char* ctl0 = alloc(NBARS * 4);      a.bars = (unsigned*)ctl0;
    a.deg  = (float*)alloc(NN * 4);
    a.cnt  = (int*)  alloc(NN * 4);
    size_t ctl_bytes = (size_t)((char*)a.cnt + ((NN * 4 + 255) / 256 * 256) - ctl0);

    a.M      = (float*)alloc((size_t)L_LAYERS * H * MWM * 4);
    a.TX     = (float*)alloc((size_t)(T_CHEB - 1) * NN * F_IN * 4);
    a.ell_r  = (int*)  alloc((size_t)NN * MD * 4);
    a.ell_m  = (float*)alloc((size_t)NN * MD * 4);
    a.ell_ea = (float4*)alloc((size_t)NN * MD * 16);
    a.hA     = (float*)alloc((size_t)NN * H * 4);
    a.hB     = (float*)alloc((size_t)NN * H * 4);
    a.P      = (float*)alloc((size_t)NN * PW * 4);
    (void)ws_size; (void)n_in; (void)in_sizes; (void)out_size;

    hipMemsetAsync(ctl0, 0, ctl_bytes, stream);
    k_fused<<<dim3(GRID), dim3(BLK), 0, stream>>>(a);
}

// Round 7
// 417.453 us; speedup vs baseline: 4.4254x; 2.0163x over previous
//
#include <hip/hip_runtime.h>

#define NN 5000
#define EE 10000
#define F_IN 16
#define F_EDGE 4
#define H 96
#define EHD 16
#define HID3 32
#define T_CHEB 5
#define L_LAYERS 10
#define C_OUT 3
#define LN_EPSF 1e-5f
#define MWM 576   // 4 attr mats + const mat + root mat
#define PW 480    // P stores the 5 edge-relevant col-blocks
#define MD 32     // ELL max in-degree (dataset max ~13)
#define BM 32     // rows per layer-kernel block
#define NB_T 157  // ceil(5000/32)

// ================= front-end: fused M precompute + ELL setup =================
__global__ void k_front(const float* __restrict__ enc_w, const float* __restrict__ enc_b,
                        const float* __restrict__ w1, const float* __restrict__ b1,
                        const float* __restrict__ w2, const float* __restrict__ b2,
                        const float* __restrict__ root,
                        const int* __restrict__ row, const int* __restrict__ col,
                        const float* __restrict__ eattr,
                        float* __restrict__ M, float* __restrict__ deg,
                        int* __restrict__ cnt, int* __restrict__ ell_r,
                        float* __restrict__ ell_m, float4* __restrict__ ell_ea) {
    const int tid = blockIdx.x * blockDim.x + threadIdx.x;
    const int NTH = gridDim.x * blockDim.x;
    // --- M precompute ---
    for (int idx = tid; idx < L_LAYERS * H * H; idx += NTH) {
        int i = idx / (H * H);
        int m = idx % (H * H);      // m = h*96 + o
        int h = m / H, o = m % H;
        const float* w2i = w2 + (size_t)i * HID3 * H * H;
        const float* w1i = w1 + i * EHD * HID3;
        float hcol[HID3];
        #pragma unroll
        for (int k2 = 0; k2 < HID3; ++k2) hcol[k2] = w2i[(size_t)k2 * H * H + m];
        float tcol[EHD];
        #pragma unroll
        for (int ke = 0; ke < EHD; ++ke) {
            float s = 0.f;
            #pragma unroll
            for (int k2 = 0; k2 < HID3; ++k2) s += w1i[ke * HID3 + k2] * hcol[k2];
            tcol[ke] = s;
        }
        float* Mi = M + (size_t)i * H * MWM + h * MWM + o;
        #pragma unroll
        for (int f = 0; f < F_EDGE; ++f) {
            float s = 0.f;
            #pragma unroll
            for (int ke = 0; ke < EHD; ++ke) s += enc_w[f * EHD + ke] * tcol[ke];
            Mi[f * H] = s;
        }
        float c = b2[(size_t)i * H * H + m];
        #pragma unroll
        for (int ke = 0; ke < EHD; ++ke) c += enc_b[ke] * tcol[ke];
        #pragma unroll
        for (int k2 = 0; k2 < HID3; ++k2) c += b1[i * HID3 + k2] * hcol[k2];
        Mi[4 * H] = c;
        Mi[5 * H] = root[(size_t)i * H * H + m];
    }
    // --- ELL setup + masked degree ---
    for (int e = tid; e < EE; e += NTH) {
        int r = row[e], c = col[e];
        float4 ea = *(const float4*)(eattr + e * F_EDGE);
        float m = (ea.x == 0.f && r != c) ? 1.f : 0.f;
        if (m != 0.f) atomicAdd(&deg[r], 1.f);   // integer-valued: exact
        int slot = atomicAdd(&cnt[c], 1);
        int p = c * MD + slot;
        ell_r[p] = r;
        ell_m[p] = m;
        ell_ea[p] = ea;
    }
}

// ====== Cheb step: dst[c] = -scale*dinv[c]*sum_in(m*dinv[r]*src[r]) - prev[c] ======
__global__ void k_cheb_step(const int* __restrict__ cnt, const int* __restrict__ ell_r,
                            const float* __restrict__ ell_m, const float* __restrict__ deg,
                            const float* __restrict__ src, const float* __restrict__ prev,
                            float* __restrict__ dst, float scale) {
    int t = blockIdx.x * blockDim.x + threadIdx.x;
    if (t >= NN * 4) return;
    int c = t >> 2, q = t & 3;
    int n = cnt[c];
    const int* rp = ell_r + c * MD;
    const float* mp = ell_m + c * MD;
    float4 acc = make_float4(0.f, 0.f, 0.f, 0.f);
    for (int p = 0; p < n; ++p) {
        float m = mp[p];
        if (m == 0.f) continue;
        int r = rp[p];
        float w = rsqrtf(deg[r]);
        float4 s = *(const float4*)(src + (size_t)r * F_IN + q * 4);
        acc.x = fmaf(w, s.x, acc.x); acc.y = fmaf(w, s.y, acc.y);
        acc.z = fmaf(w, s.z, acc.z); acc.w = fmaf(w, s.w, acc.w);
    }
    float dc = deg[c];
    float f = dc > 0.f ? -scale * rsqrtf(dc) : 0.f;
    float4 o = make_float4(f * acc.x, f * acc.y, f * acc.z, f * acc.w);
    if (prev) {
        float4 pv = *(const float4*)(prev + (size_t)c * F_IN + q * 4);
        o.x -= pv.x; o.y -= pv.y; o.z -= pv.z; o.w -= pv.w;
    }
    *(float4*)(dst + (size_t)c * F_IN + q * 4) = o;
}

// ====== Cheb step 4 fused with cheb_out: T4 for own 64 nodes, then hA rows ======
__global__ __launch_bounds__(256) void k_cheb4_out(
        const int* __restrict__ cnt, const int* __restrict__ ell_r,
        const float* __restrict__ ell_m, const float* __restrict__ deg,
        const float* __restrict__ x, const float* __restrict__ T1,
        const float* __restrict__ T2, const float* __restrict__ T3,
        float* __restrict__ T4, const float* __restrict__ cheb_w,
        const float* __restrict__ cheb_b, float* __restrict__ hout) {
    __shared__ float wlds[T_CHEB * F_IN][H];   // 30 KB
    const int n0 = blockIdx.x * 64;
    const int t = threadIdx.x;
    // stage cheb_w
    for (int i = t; i < T_CHEB * F_IN * H / 4; i += 256)
        ((float4*)wlds)[i] = ((const float4*)cheb_w)[i];
    // part 1: T4 = 2*L(T3) - T2 for own nodes
    {
        int c = n0 + (t >> 2), q = t & 3;
        if (c < NN) {
            int n = cnt[c];
            const int* rp = ell_r + c * MD;
            const float* mp = ell_m + c * MD;
            float4 acc = make_float4(0.f, 0.f, 0.f, 0.f);
            for (int p = 0; p < n; ++p) {
                float m = mp[p];
                if (m == 0.f) continue;
                int r = rp[p];
                float w = rsqrtf(deg[r]);
                float4 s = *(const float4*)(T3 + (size_t)r * F_IN + q * 4);
                acc.x = fmaf(w, s.x, acc.x); acc.y = fmaf(w, s.y, acc.y);
                acc.z = fmaf(w, s.z, acc.z); acc.w = fmaf(w, s.w, acc.w);
            }
            float dc = deg[c];
            float f = dc > 0.f ? -2.f * rsqrtf(dc) : 0.f;
            float4 pv = *(const float4*)(T2 + (size_t)c * F_IN + q * 4);
            float4 o = make_float4(f * acc.x - pv.x, f * acc.y - pv.y,
                                   f * acc.z - pv.z, f * acc.w - pv.w);
            *(float4*)(T4 + (size_t)c * F_IN + q * 4) = o;
        }
    }
    __syncthreads();
    // part 2: hA rows for own nodes (4 threads/node, 24 cols each)
    {
        int n = n0 + (t >> 2), cseg = t & 3;
        if (n >= NN) return;
        float txv[T_CHEB * F_IN];
        #pragma unroll
        for (int q = 0; q < 4; ++q) {
            *(float4*)(txv + q * 4)      = *(const float4*)(x  + (size_t)n * F_IN + q * 4);
            *(float4*)(txv + 16 + q * 4) = *(const float4*)(T1 + (size_t)n * F_IN + q * 4);
            *(float4*)(txv + 32 + q * 4) = *(const float4*)(T2 + (size_t)n * F_IN + q * 4);
            *(float4*)(txv + 48 + q * 4) = *(const float4*)(T3 + (size_t)n * F_IN + q * 4);
            *(float4*)(txv + 64 + q * 4) = *(const float4*)(T4 + (size_t)n * F_IN + q * 4);
        }
        float* hr = hout + (size_t)n * H + cseg * 24;
        #pragma unroll 4
        for (int c = 0; c < 24; ++c) {
            int o = cseg * 24 + c;
            float s = cheb_b[o];
            #pragma unroll
            for (int kf = 0; kf < T_CHEB * F_IN; ++kf)
                s = fmaf(txv[kf], wlds[kf][o], s);
            hr[c] = s;
        }
    }
}

// ====== per-layer: gather(P_prev) + LN/ReLU + GEMM -> P_out, base_out ======
// grid (157, 2): 32-node tiles x column halves (3 jb each). mode: 0=layer0, 1=rest
__global__ __launch_bounds__(256) void k_layer(
        const float* __restrict__ basePrev, const float* __restrict__ Pprev,
        const int* __restrict__ cnt, const int* __restrict__ ell_r,
        const float4* __restrict__ ell_ea, const float* __restrict__ Mi,
        const float* __restrict__ cb, const float* __restrict__ lg,
        const float* __restrict__ lb,
        float* __restrict__ Pout, float* __restrict__ baseOut, int mode) {
    __shared__ float hs[BM][100];    // 12.8 KB (+4 pad)
    __shared__ float hres[BM][96];   // 12 KB (residual, pre-LN)
    __shared__ float Mt[16][96];     // 6 KB
    const int n0 = blockIdx.x * BM;
    const int half = blockIdx.y;
    const int t = threadIdx.x;

    // ---- load base + gather messages into hs ----
    for (int it = t; it < BM * 12; it += 256) {
        int r = it / 12, g = it % 12;
        int gn = n0 + r, o = g * 8;
        float s[8] = {0.f, 0.f, 0.f, 0.f, 0.f, 0.f, 0.f, 0.f};
        if (gn < NN) {
            const float* bp = basePrev + (size_t)gn * H + o;
            *(float4*)(s + 0) = *(const float4*)(bp + 0);
            *(float4*)(s + 4) = *(const float4*)(bp + 4);
            if (mode) {
                int nc = cnt[gn];
                const int* rp = ell_r + gn * MD;
                const float4* eap = ell_ea + gn * MD;
                for (int p = 0; p < nc; ++p) {
                    int r2 = rp[p];
                    float4 ea = eap[p];
                    const float* pb = Pprev + (size_t)r2 * PW + o;
                    float4 c0 = *(const float4*)(pb + 384);
                    float4 c1 = *(const float4*)(pb + 388);
                    s[0] += c0.x; s[1] += c0.y; s[2] += c0.z; s[3] += c0.w;
                    s[4] += c1.x; s[5] += c1.y; s[6] += c1.z; s[7] += c1.w;
                    const float cf[4] = {ea.x, ea.y, ea.z, ea.w};
                    #pragma unroll
                    for (int f = 0; f < 4; ++f) {
                        float4 p0 = *(const float4*)(pb + f * 96);
                        float4 p1 = *(const float4*)(pb + f * 96 + 4);
                        s[0] = fmaf(cf[f], p0.x, s[0]); s[1] = fmaf(cf[f], p0.y, s[1]);
                        s[2] = fmaf(cf[f], p0.z, s[2]); s[3] = fmaf(cf[f], p0.w, s[3]);
                        s[4] = fmaf(cf[f], p1.x, s[4]); s[5] = fmaf(cf[f], p1.y, s[5]);
                        s[6] = fmaf(cf[f], p1.z, s[6]); s[7] = fmaf(cf[f], p1.w, s[7]);
                    }
                }
            }
        }
        *(float4*)&hs[r][o] = *(const float4*)(s + 0);
        *(float4*)&hs[r][o + 4] = *(const float4*)(s + 4);
    }
    __syncthreads();

    // ---- save residual + LayerNorm + ReLU (in LDS) ----
    if (mode) {
        int r = t >> 3, l8 = t & 7;   // 32 rows x 8 lanes x 12 cols
        float xv[12];
        *(float4*)(xv + 0) = *(const float4*)&hs[r][l8 * 12 + 0];
        *(float4*)(xv + 4) = *(const float4*)&hs[r][l8 * 12 + 4];
        *(float4*)(xv + 8) = *(const float4*)&hs[r][l8 * 12 + 8];
        *(float4*)&hres[r][l8 * 12 + 0] = *(const float4*)(xv + 0);
        *(float4*)&hres[r][l8 * 12 + 4] = *(const float4*)(xv + 4);
        *(float4*)&hres[r][l8 * 12 + 8] = *(const float4*)(xv + 8);
        float s = 0.f;
        #pragma unroll
        for (int i = 0; i < 12; ++i) s += xv[i];
        s += __shfl_xor(s, 1); s += __shfl_xor(s, 2); s += __shfl_xor(s, 4);
        float mu = s * (1.0f / H);
        float vv = 0.f;
        #pragma unroll
        for (int i = 0; i < 12; ++i) { float d = xv[i] - mu; vv += d * d; }
        vv += __shfl_xor(vv, 1); vv += __shfl_xor(vv, 2); vv += __shfl_xor(vv, 4);
        float is = rsqrtf(vv * (1.0f / H) + LN_EPSF);
        const float* gp = lg + l8 * 12;
        const float* bp = lb + l8 * 12;
        float yv[12];
        #pragma unroll
        for (int i = 0; i < 12; ++i)
            yv[i] = fmaxf(fmaf((xv[i] - mu) * is, gp[i], bp[i]), 0.f);
        *(float4*)&hs[r][l8 * 12 + 0] = *(const float4*)(yv + 0);
        *(float4*)&hs[r][l8 * 12 + 4] = *(const float4*)(yv + 4);
        *(float4*)&hs[r][l8 * 12 + 8] = *(const float4*)(yv + 8);
        __syncthreads();
    }

    // ---- GEMM: 32 x 96 x (3 jb of 96 cols) ----
    const int tx = t & 15, ty = t >> 4;   // tx: 6 cols, ty: 2 rows
    for (int jbi = 0; jbi < 3; ++jbi) {
        int jb = half * 3 + jbi, j0 = jb * 96;
        float acc[2][6] = {};
        for (int k0 = 0; k0 < H; k0 += 16) {
            for (int idx = t; idx < 384; idx += 256) {
                int kk = idx / 24, jj = (idx % 24) * 4;
                *(float4*)&Mt[kk][jj] =
                    *(const float4*)(Mi + (size_t)(k0 + kk) * MWM + j0 + jj);
            }
            __syncthreads();
            #pragma unroll
            for (int kk = 0; kk < 16; ++kk) {
                float aa[2], bb[6];
                aa[0] = hs[ty * 2 + 0][k0 + kk];
                aa[1] = hs[ty * 2 + 1][k0 + kk];
                *(float2*)(bb + 0) = *(const float2*)&Mt[kk][tx * 6 + 0];
                *(float2*)(bb + 2) = *(const float2*)&Mt[kk][tx * 6 + 2];
                *(float2*)(bb + 4) = *(const float2*)&Mt[kk][tx * 6 + 4];
                #pragma unroll
                for (int i2 = 0; i2 < 2; ++i2)
                    #pragma unroll
                    for (int j = 0; j < 6; ++j)
                        acc[i2][j] = fmaf(aa[i2], bb[j], acc[i2][j]);
            }
            __syncthreads();
        }
        if (jb < 5) {
            #pragma unroll
            for (int i2 = 0; i2 < 2; ++i2) {
                int gn = n0 + ty * 2 + i2;
                if (gn < NN) {
                    float* pr = Pout + (size_t)gn * PW + j0 + tx * 6;
                    *(float2*)(pr + 0) = make_float2(acc[i2][0], acc[i2][1]);
                    *(float2*)(pr + 2) = make_float2(acc[i2][2], acc[i2][3]);
                    *(float2*)(pr + 4) = make_float2(acc[i2][4], acc[i2][5]);
                }
            }
        } else {
            #pragma unroll
            for (int i2 = 0; i2 < 2; ++i2) {
                int gn = n0 + ty * 2 + i2;
                if (gn < NN) {
                    int ob = tx * 6;
                    float* hp = baseOut + (size_t)gn * H + ob;
                    int r = ty * 2 + i2;
                    #pragma unroll
                    for (int j = 0; j < 6; ++j)
                        hp[j] = acc[i2][j] + cb[ob + j] + (mode ? hres[r][ob + j] : 0.f);
                }
            }
        }
    }
}

// ====== final: gather h9 + LN(params0) + relu + linear(96->3) ======
__global__ void k_final(const float* __restrict__ base, const float* __restrict__ P,
                        const int* __restrict__ cnt, const int* __restrict__ ell_r,
                        const float4* __restrict__ ell_ea,
                        const float* __restrict__ g, const float* __restrict__ b,
                        const float* __restrict__ lin_w, const float* __restrict__ lin_b,
                        float* __restrict__ out) {
    int tid = blockIdx.x * blockDim.x + threadIdx.x;
    int n = tid >> 3, l8 = tid & 7;
    if (n >= NN) return;
    int o = l8 * 12;
    float xv[12];
    {
        const float* bp = base + (size_t)n * H + o;
        *(float4*)(xv + 0) = *(const float4*)(bp + 0);
        *(float4*)(xv + 4) = *(const float4*)(bp + 4);
        *(float4*)(xv + 8) = *(const float4*)(bp + 8);
        int nc = cnt[n];
        const int* rp = ell_r + n * MD;
        const float4* eap = ell_ea + n * MD;
        for (int p = 0; p < nc; ++p) {
            int r2 = rp[p];
            float4 ea = eap[p];
            const float* pb = P + (size_t)r2 * PW + o;
            const float cf[4] = {ea.x, ea.y, ea.z, ea.w};
            #pragma unroll
            for (int q = 0; q < 3; ++q) {
                float4 c0 = *(const float4*)(pb + 384 + q * 4);
                xv[q * 4 + 0] += c0.x; xv[q * 4 + 1] += c0.y;
                xv[q * 4 + 2] += c0.z; xv[q * 4 + 3] += c0.w;
                #pragma unroll
                for (int f = 0; f < 4; ++f) {
                    float4 p0 = *(const float4*)(pb + f * 96 + q * 4);
                    xv[q * 4 + 0] = fmaf(cf[f], p0.x, xv[q * 4 + 0]);
                    xv[q * 4 + 1] = fmaf(cf[f], p0.y, xv[q * 4 + 1]);
                    xv[q * 4 + 2] = fmaf(cf[f], p0.z, xv[q * 4 + 2]);
                    xv[q * 4 + 3] = fmaf(cf[f], p0.w, xv[q * 4 + 3]);
                }
            }
        }
    }
    float s = 0.f;
    #pragma unroll
    for (int i = 0; i < 12; ++i) s += xv[i];
    s += __shfl_xor(s, 1); s += __shfl_xor(s, 2); s += __shfl_xor(s, 4);
    float mu = s * (1.0f / H);
    float vv = 0.f;
    #pragma unroll
    for (int i = 0; i < 12; ++i) { float d = xv[i] - mu; vv += d * d; }
    vv += __shfl_xor(vv, 1); vv += __shfl_xor(vv, 2); vv += __shfl_xor(vv, 4);
    float is = rsqrtf(vv * (1.0f / H) + LN_EPSF);
    const float* gp = g + o;
    const float* bp = b + o;
    float a0 = 0.f, a1 = 0.f, a2 = 0.f;
    #pragma unroll
    for (int i = 0; i < 12; ++i) {
        float tt = fmaxf(fmaf((xv[i] - mu) * is, gp[i], bp[i]), 0.f);
        int oo = o + i;
        a0 = fmaf(tt, lin_w[oo * C_OUT + 0], a0);
        a1 = fmaf(tt, lin_w[oo * C_OUT + 1], a1);
        a2 = fmaf(tt, lin_w[oo * C_OUT + 2], a2);
    }
    a0 += __shfl_xor(a0, 1); a0 += __shfl_xor(a0, 2); a0 += __shfl_xor(a0, 4);
    a1 += __shfl_xor(a1, 1); a1 += __shfl_xor(a1, 2); a1 += __shfl_xor(a1, 4);
    a2 += __shfl_xor(a2, 1); a2 += __shfl_xor(a2, 2); a2 += __shfl_xor(a2, 4);
    if (l8 == 0) {
        out[n * C_OUT + 0] = a0 + lin_b[0];
        out[n * C_OUT + 1] = a1 + lin_b[1];
        out[n * C_OUT + 2] = a2 + lin_b[2];
    }
}

extern "C" void kernel_launch(void* const* d_in, const int* in_sizes, int n_in,
                              void* d_out, int out_size, void* d_ws, size_t ws_size,
                              hipStream_t stream) {
    const float* x      = (const float*)d_in[0];
    const int*   row    = (const int*)d_in[1];
    const int*   col    = (const int*)d_in[1] + EE;
    const float* eattr  = (const float*)d_in[2];
    const float* cheb_w = (const float*)d_in[3];
    const float* cheb_b = (const float*)d_in[4];
    const float* enc_w  = (const float*)d_in[5];
    const float* enc_b  = (const float*)d_in[6];
    const float* w1     = (const float*)d_in[7];
    const float* b1     = (const float*)d_in[8];
    const float* w2     = (const float*)d_in[9];
    const float* b2     = (const float*)d_in[10];
    const float* root   = (const float*)d_in[11];
    const float* conv_b = (const float*)d_in[12];
    const float* ln_g   = (const float*)d_in[13];
    const float* ln_b   = (const float*)d_in[14];
    const float* lin_w  = (const float*)d_in[15];
    const float* lin_b  = (const float*)d_in[16];

    char* base = (char*)d_ws;
    size_t off = 0;
    auto alloc = [&](size_t nbytes) {
        char* p = base + off;
        off += (nbytes + 255) / 256 * 256;
        return p;
    };
    // control region (deg + cnt), zeroed with one memset
    float*  deg    = (float*)alloc(NN * 4);
    int*    cnt    = (int*)  alloc(NN * 4);
    size_t  ctl_bytes = off;
    float*  M      = (float*)alloc((size_t)L_LAYERS * H * MWM * 4);
    float*  TX     = (float*)alloc((size_t)(T_CHEB - 1) * NN * F_IN * 4);
    int*    ell_r  = (int*)  alloc((size_t)NN * MD * 4);
    float*  ell_m  = (float*)alloc((size_t)NN * MD * 4);
    float4* ell_ea = (float4*)alloc((size_t)NN * MD * 16);
    float*  bA     = (float*)alloc((size_t)NN * H * 4);   // baseBuf[0] (also hA)
    float*  bB     = (float*)alloc((size_t)NN * H * 4);   // baseBuf[1]
    float*  P0     = (float*)alloc((size_t)NN * PW * 4);
    float*  P1     = (float*)alloc((size_t)NN * PW * 4);
    (void)ws_size; (void)n_in; (void)in_sizes; (void)out_size;

    const int B = 256;
    auto G = [](long n, int b) { return (int)((n + b - 1) / b); };

    hipMemsetAsync(deg, 0, ctl_bytes, stream);
    k_front<<<360, B, 0, stream>>>(enc_w, enc_b, w1, b1, w2, b2, root,
                                   row, col, eattr, M, deg, cnt, ell_r, ell_m, ell_ea);

    // Cheb: T1..T3 standalone, T4 fused with cheb_out -> bA
    float* T1 = (float*)TX;
    float* T2 = T1 + (size_t)NN * F_IN;
    float* T3 = T2 + (size_t)NN * F_IN;
    float* T4 = T3 + (size_t)NN * F_IN;
    k_cheb_step<<<G((long)NN * 4, B), B, 0, stream>>>(cnt, ell_r, ell_m, deg, x,  nullptr, T1, 1.f);
    k_cheb_step<<<G((long)NN * 4, B), B, 0, stream>>>(cnt, ell_r, ell_m, deg, T1, x,       T2, 2.f);
    k_cheb_step<<<G((long)NN * 4, B), B, 0, stream>>>(cnt, ell_r, ell_m, deg, T2, T1,      T3, 2.f);
    k_cheb4_out<<<G(NN, 64), B, 0, stream>>>(cnt, ell_r, ell_m, deg, x, T1, T2, T3, T4,
                                             cheb_w, cheb_b, bA);

    // layers: K_i reads baseBuf[i&1], P[(i+1)&1]; writes baseBuf[(i+1)&1], P[i&1]
    float* baseBuf[2] = { bA, bB };
    float* Pbuf[2]    = { P0, P1 };
    for (int li = 0; li < L_LAYERS; ++li) {
        k_layer<<<dim3(NB_T, 2), B, 0, stream>>>(
            baseBuf[li & 1], Pbuf[(li + 1) & 1], cnt, ell_r, ell_ea,
            M + (size_t)li * H * MWM, conv_b + li * H, ln_g + li * H, ln_b + li * H,
            Pbuf[li & 1], baseBuf[(li + 1) & 1], li > 0 ? 1 : 0);
    }

    // final: base = baseBuf[10&1]=bA, P = Pbuf[9&1]=P1
    k_final<<<G((long)NN * 8, B), B, 0, stream>>>(baseBuf[0], Pbuf[1], cnt, ell_r, ell_ea,
                                                  ln_g, ln_b, lin_w, lin_b, (float*)d_out);
}

// Round 8
// 330.743 us; speedup vs baseline: 5.5857x; 1.2622x over previous
//
#include <hip/hip_runtime.h>

#define NN 5000
#define EE 10000
#define F_IN 16
#define F_EDGE 4
#define H 96
#define EHD 16
#define HID3 32
#define T_CHEB 5
#define L_LAYERS 10
#define C_OUT 3
#define LN_EPSF 1e-5f
#define MWM 576   // 4 attr mats + const mat + root mat
#define PW 480    // P stores the 5 edge-relevant col-blocks
#define MD 32     // ELL max in-degree (dataset max ~13)
#define BM 32     // rows per layer tile
#define NBT 157   // ceil(5000/32)
#define NW (NBT * 6)        // 942 work items
#define GPAD 944            // padded to 8*118 for XCD-chunked swizzle
#define CPX 118             // chunks per XCD

// ================= front-end: fused M precompute + ELL setup =================
__global__ void k_front(const float* __restrict__ enc_w, const float* __restrict__ enc_b,
                        const float* __restrict__ w1, const float* __restrict__ b1,
                        const float* __restrict__ w2, const float* __restrict__ b2,
                        const float* __restrict__ root,
                        const int* __restrict__ row, const int* __restrict__ col,
                        const float* __restrict__ eattr,
                        float* __restrict__ M, float* __restrict__ deg,
                        int* __restrict__ cnt, int* __restrict__ ell_r,
                        float* __restrict__ ell_m, float4* __restrict__ ell_ea) {
    const int tid = blockIdx.x * blockDim.x + threadIdx.x;
    const int NTH = gridDim.x * blockDim.x;
    for (int idx = tid; idx < L_LAYERS * H * H; idx += NTH) {
        int i = idx / (H * H);
        int m = idx % (H * H);      // m = h*96 + o
        int h = m / H, o = m % H;
        const float* w2i = w2 + (size_t)i * HID3 * H * H;
        const float* w1i = w1 + i * EHD * HID3;
        float hcol[HID3];
        #pragma unroll
        for (int k2 = 0; k2 < HID3; ++k2) hcol[k2] = w2i[(size_t)k2 * H * H + m];
        float tcol[EHD];
        #pragma unroll
        for (int ke = 0; ke < EHD; ++ke) {
            float s = 0.f;
            #pragma unroll
            for (int k2 = 0; k2 < HID3; ++k2) s += w1i[ke * HID3 + k2] * hcol[k2];
            tcol[ke] = s;
        }
        float* Mi = M + (size_t)i * H * MWM + h * MWM + o;
        #pragma unroll
        for (int f = 0; f < F_EDGE; ++f) {
            float s = 0.f;
            #pragma unroll
            for (int ke = 0; ke < EHD; ++ke) s += enc_w[f * EHD + ke] * tcol[ke];
            Mi[f * H] = s;
        }
        float c = b2[(size_t)i * H * H + m];
        #pragma unroll
        for (int ke = 0; ke < EHD; ++ke) c += enc_b[ke] * tcol[ke];
        #pragma unroll
        for (int k2 = 0; k2 < HID3; ++k2) c += b1[i * HID3 + k2] * hcol[k2];
        Mi[4 * H] = c;
        Mi[5 * H] = root[(size_t)i * H * H + m];
    }
    for (int e = tid; e < EE; e += NTH) {
        int r = row[e], c = col[e];
        float4 ea = *(const float4*)(eattr + e * F_EDGE);
        float m = (ea.x == 0.f && r != c) ? 1.f : 0.f;
        if (m != 0.f) atomicAdd(&deg[r], 1.f);   // integer-valued: exact
        int slot = atomicAdd(&cnt[c], 1);
        int p = c * MD + slot;
        ell_r[p] = r;
        ell_m[p] = m;
        ell_ea[p] = ea;
    }
}

// ====== Cheb step ======
__global__ void k_cheb_step(const int* __restrict__ cnt, const int* __restrict__ ell_r,
                            const float* __restrict__ ell_m, const float* __restrict__ deg,
                            const float* __restrict__ src, const float* __restrict__ prev,
                            float* __restrict__ dst, float scale) {
    int t = blockIdx.x * blockDim.x + threadIdx.x;
    if (t >= NN * 4) return;
    int c = t >> 2, q = t & 3;
    int n = cnt[c];
    const int* rp = ell_r + c * MD;
    const float* mp = ell_m + c * MD;
    float4 acc = make_float4(0.f, 0.f, 0.f, 0.f);
    for (int p = 0; p < n; ++p) {
        float m = mp[p];
        if (m == 0.f) continue;
        int r = rp[p];
        float w = rsqrtf(deg[r]);
        float4 s = *(const float4*)(src + (size_t)r * F_IN + q * 4);
        acc.x = fmaf(w, s.x, acc.x); acc.y = fmaf(w, s.y, acc.y);
        acc.z = fmaf(w, s.z, acc.z); acc.w = fmaf(w, s.w, acc.w);
    }
    float dc = deg[c];
    float f = dc > 0.f ? -scale * rsqrtf(dc) : 0.f;
    float4 o = make_float4(f * acc.x, f * acc.y, f * acc.z, f * acc.w);
    if (prev) {
        float4 pv = *(const float4*)(prev + (size_t)c * F_IN + q * 4);
        o.x -= pv.x; o.y -= pv.y; o.z -= pv.z; o.w -= pv.w;
    }
    *(float4*)(dst + (size_t)c * F_IN + q * 4) = o;
}

// ====== Cheb step 4 fused with cheb_out ======
__global__ __launch_bounds__(256) void k_cheb4_out(
        const int* __restrict__ cnt, const int* __restrict__ ell_r,
        const float* __restrict__ ell_m, const float* __restrict__ deg,
        const float* __restrict__ x, const float* __restrict__ T1,
        const float* __restrict__ T2, const float* __restrict__ T3,
        float* __restrict__ T4, const float* __restrict__ cheb_w,
        const float* __restrict__ cheb_b, float* __restrict__ hout) {
    __shared__ float wlds[T_CHEB * F_IN][H];   // 30 KB
    const int n0 = blockIdx.x * 64;
    const int t = threadIdx.x;
    for (int i = t; i < T_CHEB * F_IN * H / 4; i += 256)
        ((float4*)wlds)[i] = ((const float4*)cheb_w)[i];
    {
        int c = n0 + (t >> 2), q = t & 3;
        if (c < NN) {
            int n = cnt[c];
            const int* rp = ell_r + c * MD;
            const float* mp = ell_m + c * MD;
            float4 acc = make_float4(0.f, 0.f, 0.f, 0.f);
            for (int p = 0; p < n; ++p) {
                float m = mp[p];
                if (m == 0.f) continue;
                int r = rp[p];
                float w = rsqrtf(deg[r]);
                float4 s = *(const float4*)(T3 + (size_t)r * F_IN + q * 4);
                acc.x = fmaf(w, s.x, acc.x); acc.y = fmaf(w, s.y, acc.y);
                acc.z = fmaf(w, s.z, acc.z); acc.w = fmaf(w, s.w, acc.w);
            }
            float dc = deg[c];
            float f = dc > 0.f ? -2.f * rsqrtf(dc) : 0.f;
            float4 pv = *(const float4*)(T2 + (size_t)c * F_IN + q * 4);
            float4 o = make_float4(f * acc.x - pv.x, f * acc.y - pv.y,
                                   f * acc.z - pv.z, f * acc.w - pv.w);
            *(float4*)(T4 + (size_t)c * F_IN + q * 4) = o;
        }
    }
    __syncthreads();
    {
        int n = n0 + (t >> 2), cseg = t & 3;
        if (n >= NN) return;
        float txv[T_CHEB * F_IN];
        #pragma unroll
        for (int q = 0; q < 4; ++q) {
            *(float4*)(txv + q * 4)      = *(const float4*)(x  + (size_t)n * F_IN + q * 4);
            *(float4*)(txv + 16 + q * 4) = *(const float4*)(T1 + (size_t)n * F_IN + q * 4);
            *(float4*)(txv + 32 + q * 4) = *(const float4*)(T2 + (size_t)n * F_IN + q * 4);
            *(float4*)(txv + 48 + q * 4) = *(const float4*)(T3 + (size_t)n * F_IN + q * 4);
            *(float4*)(txv + 64 + q * 4) = *(const float4*)(T4 + (size_t)n * F_IN + q * 4);
        }
        float* hr = hout + (size_t)n * H + cseg * 24;
        #pragma unroll 4
        for (int c = 0; c < 24; ++c) {
            int o = cseg * 24 + c;
            float s = cheb_b[o];
            #pragma unroll
            for (int kf = 0; kf < T_CHEB * F_IN; ++kf)
                s = fmaf(txv[kf], wlds[kf][o], s);
            hr[c] = s;
        }
    }
}

// ====== per-layer fused: gather + LN/ReLU + GEMM (32-row x 96-col tiles) ======
// grid 944 (XCD-chunked swizzle onto 157x6 work items), 256 threads.
__global__ __launch_bounds__(256) void k_layer(
        const float* __restrict__ basePrev, const float* __restrict__ Pprev,
        const float* __restrict__ vsrc0,
        const int* __restrict__ cnt, const int* __restrict__ ell_r,
        const float4* __restrict__ ell_ea, const float* __restrict__ Mi,
        const float* __restrict__ cb, const float* __restrict__ lg,
        const float* __restrict__ lb,
        float* __restrict__ Pout, float* __restrict__ baseOut, int mode) {
    // chunked XCD swizzle: consecutive work items (same row-tile) -> same XCD
    int w = (blockIdx.x & 7) * CPX + (blockIdx.x >> 3);
    if (w >= NW) return;
    const int nb = w / 6, jb = w % 6;
    const int n0 = nb * BM, j0 = jb * 96;
    const int t = threadIdx.x;

    __shared__ float vsT[96][36];    // transposed v tile, stride 36 (13.8 KB)
    __shared__ float Mt[16][96];     // 6.1 KB
    __shared__ float hgat[BM][100];  // gathered h (residual), 12.8 KB

    // ---- build v tile (8 threads/node, 12 cols each) ----
    {
        int r = t >> 3, l8 = t & 7;
        int gn = n0 + r, o = l8 * 12;
        float xv[12] = {0,0,0,0,0,0,0,0,0,0,0,0};
        if (gn < NN) {
            if (mode) {
                const float* bp = basePrev + (size_t)gn * H + o;
                *(float4*)(xv + 0) = *(const float4*)(bp + 0);
                *(float4*)(xv + 4) = *(const float4*)(bp + 4);
                *(float4*)(xv + 8) = *(const float4*)(bp + 8);
                int nc = cnt[gn];
                const int* rp = ell_r + gn * MD;
                const float4* eap = ell_ea + gn * MD;
                for (int p = 0; p < nc; ++p) {
                    int r2 = rp[p];
                    float4 ea = eap[p];
                    const float* pb = Pprev + (size_t)r2 * PW + o;
                    #pragma unroll
                    for (int q = 0; q < 3; ++q) {
                        float4 c0 = *(const float4*)(pb + 384 + q * 4);
                        xv[q*4+0] += c0.x; xv[q*4+1] += c0.y;
                        xv[q*4+2] += c0.z; xv[q*4+3] += c0.w;
                    }
                    const float cf[4] = {ea.x, ea.y, ea.z, ea.w};
                    #pragma unroll
                    for (int f = 0; f < 4; ++f) {
                        #pragma unroll
                        for (int q = 0; q < 3; ++q) {
                            float4 p0 = *(const float4*)(pb + f * 96 + q * 4);
                            xv[q*4+0] = fmaf(cf[f], p0.x, xv[q*4+0]);
                            xv[q*4+1] = fmaf(cf[f], p0.y, xv[q*4+1]);
                            xv[q*4+2] = fmaf(cf[f], p0.z, xv[q*4+2]);
                            xv[q*4+3] = fmaf(cf[f], p0.w, xv[q*4+3]);
                        }
                    }
                }
            } else {
                const float* bp = vsrc0 + (size_t)gn * H + o;
                *(float4*)(xv + 0) = *(const float4*)(bp + 0);
                *(float4*)(xv + 4) = *(const float4*)(bp + 4);
                *(float4*)(xv + 8) = *(const float4*)(bp + 8);
            }
        }
        if (mode) {
            // save residual
            *(float4*)&hgat[r][o + 0] = *(const float4*)(xv + 0);
            *(float4*)&hgat[r][o + 4] = *(const float4*)(xv + 4);
            *(float4*)&hgat[r][o + 8] = *(const float4*)(xv + 8);
            // LayerNorm + ReLU (8-lane reduce)
            float s = 0.f;
            #pragma unroll
            for (int i = 0; i < 12; ++i) s += xv[i];
            s += __shfl_xor(s, 1); s += __shfl_xor(s, 2); s += __shfl_xor(s, 4);
            float mu = s * (1.0f / H);
            float vv = 0.f;
            #pragma unroll
            for (int i = 0; i < 12; ++i) { float d = xv[i] - mu; vv += d * d; }
            vv += __shfl_xor(vv, 1); vv += __shfl_xor(vv, 2); vv += __shfl_xor(vv, 4);
            float is = rsqrtf(vv * (1.0f / H) + LN_EPSF);
            const float* gp = lg + o;
            const float* bp2 = lb + o;
            #pragma unroll
            for (int i = 0; i < 12; ++i)
                xv[i] = fmaxf(fmaf((xv[i] - mu) * is, gp[i], bp2[i]), 0.f);
        }
        #pragma unroll
        for (int i = 0; i < 12; ++i) vsT[o + i][r] = xv[i];
    }
    __syncthreads();

    // ---- GEMM: acc[2][6], rowg = t>>4 (16 x 2 rows), colg = t&15 (16 x 6 cols) ----
    const int colg = t & 15, rowg = t >> 4;
    float acc[2][6] = {};
    for (int k0 = 0; k0 < H; k0 += 16) {
        for (int i = t; i < 384; i += 256) {
            int kk = i / 24, jj = (i % 24) * 4;
            *(float4*)&Mt[kk][jj] = *(const float4*)(Mi + (size_t)(k0 + kk) * MWM + j0 + jj);
        }
        __syncthreads();
        #pragma unroll
        for (int kk = 0; kk < 16; ++kk) {
            float2 av = *(const float2*)&vsT[k0 + kk][rowg * 2];
            float2 b0 = *(const float2*)&Mt[kk][colg * 6 + 0];
            float2 b1 = *(const float2*)&Mt[kk][colg * 6 + 2];
            float2 b2 = *(const float2*)&Mt[kk][colg * 6 + 4];
            acc[0][0] = fmaf(av.x, b0.x, acc[0][0]); acc[0][1] = fmaf(av.x, b0.y, acc[0][1]);
            acc[0][2] = fmaf(av.x, b1.x, acc[0][2]); acc[0][3] = fmaf(av.x, b1.y, acc[0][3]);
            acc[0][4] = fmaf(av.x, b2.x, acc[0][4]); acc[0][5] = fmaf(av.x, b2.y, acc[0][5]);
            acc[1][0] = fmaf(av.y, b0.x, acc[1][0]); acc[1][1] = fmaf(av.y, b0.y, acc[1][1]);
            acc[1][2] = fmaf(av.y, b1.x, acc[1][2]); acc[1][3] = fmaf(av.y, b1.y, acc[1][3]);
            acc[1][4] = fmaf(av.y, b2.x, acc[1][4]); acc[1][5] = fmaf(av.y, b2.y, acc[1][5]);
        }
        __syncthreads();
    }

    // ---- epilogue ----
    if (jb < 5) {
        #pragma unroll
        for (int i = 0; i < 2; ++i) {
            int gn = n0 + rowg * 2 + i;
            if (gn < NN) {
                float* pr = Pout + (size_t)gn * PW + j0 + colg * 6;
                *(float2*)(pr + 0) = make_float2(acc[i][0], acc[i][1]);
                *(float2*)(pr + 2) = make_float2(acc[i][2], acc[i][3]);
                *(float2*)(pr + 4) = make_float2(acc[i][4], acc[i][5]);
            }
        }
    } else {
        #pragma unroll
        for (int i = 0; i < 2; ++i) {
            int gn = n0 + rowg * 2 + i;
            if (gn < NN) {
                int r = rowg * 2 + i, ob = colg * 6;
                float* hp = baseOut + (size_t)gn * H + ob;
                #pragma unroll
                for (int j = 0; j < 6; ++j)
                    hp[j] = acc[i][j] + cb[ob + j] + (mode ? hgat[r][ob + j] : 0.f);
            }
        }
    }
}

// ====== final: gather h9 + LN(params0) + relu + linear(96->3) ======
__global__ void k_final(const float* __restrict__ base, const float* __restrict__ P,
                        const int* __restrict__ cnt, const int* __restrict__ ell_r,
                        const float4* __restrict__ ell_ea,
                        const float* __restrict__ g, const float* __restrict__ b,
                        const float* __restrict__ lin_w, const float* __restrict__ lin_b,
                        float* __restrict__ out) {
    int tid = blockIdx.x * blockDim.x + threadIdx.x;
    int n = tid >> 3, l8 = tid & 7;
    if (n >= NN) return;
    int o = l8 * 12;
    float xv[12];
    {
        const float* bp = base + (size_t)n * H + o;
        *(float4*)(xv + 0) = *(const float4*)(bp + 0);
        *(float4*)(xv + 4) = *(const float4*)(bp + 4);
        *(float4*)(xv + 8) = *(const float4*)(bp + 8);
        int nc = cnt[n];
        const int* rp = ell_r + n * MD;
        const float4* eap = ell_ea + n * MD;
        for (int p = 0; p < nc; ++p) {
            int r2 = rp[p];
            float4 ea = eap[p];
            const float* pb = P + (size_t)r2 * PW + o;
            const float cf[4] = {ea.x, ea.y, ea.z, ea.w};
            #pragma unroll
            for (int q = 0; q < 3; ++q) {
                float4 c0 = *(const float4*)(pb + 384 + q * 4);
                xv[q*4+0] += c0.x; xv[q*4+1] += c0.y;
                xv[q*4+2] += c0.z; xv[q*4+3] += c0.w;
                #pragma unroll
                for (int f = 0; f < 4; ++f) {
                    float4 p0 = *(const float4*)(pb + f * 96 + q * 4);
                    xv[q*4+0] = fmaf(cf[f], p0.x, xv[q*4+0]);
                    xv[q*4+1] = fmaf(cf[f], p0.y, xv[q*4+1]);
                    xv[q*4+2] = fmaf(cf[f], p0.z, xv[q*4+2]);
                    xv[q*4+3] = fmaf(cf[f], p0.w, xv[q*4+3]);
                }
            }
        }
    }
    float s = 0.f;
    #pragma unroll
    for (int i = 0; i < 12; ++i) s += xv[i];
    s += __shfl_xor(s, 1); s += __shfl_xor(s, 2); s += __shfl_xor(s, 4);
    float mu = s * (1.0f / H);
    float vv = 0.f;
    #pragma unroll
    for (int i = 0; i < 12; ++i) { float d = xv[i] - mu; vv += d * d; }
    vv += __shfl_xor(vv, 1); vv += __shfl_xor(vv, 2); vv += __shfl_xor(vv, 4);
    float is = rsqrtf(vv * (1.0f / H) + LN_EPSF);
    const float* gp = g + o;
    const float* bp = b + o;
    float a0 = 0.f, a1 = 0.f, a2 = 0.f;
    #pragma unroll
    for (int i = 0; i < 12; ++i) {
        float tt = fmaxf(fmaf((xv[i] - mu) * is, gp[i], bp[i]), 0.f);
        int oo = o + i;
        a0 = fmaf(tt, lin_w[oo * C_OUT + 0], a0);
        a1 = fmaf(tt, lin_w[oo * C_OUT + 1], a1);
        a2 = fmaf(tt, lin_w[oo * C_OUT + 2], a2);
    }
    a0 += __shfl_xor(a0, 1); a0 += __shfl_xor(a0, 2); a0 += __shfl_xor(a0, 4);
    a1 += __shfl_xor(a1, 1); a1 += __shfl_xor(a1, 2); a1 += __shfl_xor(a1, 4);
    a2 += __shfl_xor(a2, 1); a2 += __shfl_xor(a2, 2); a2 += __shfl_xor(a2, 4);
    if (l8 == 0) {
        out[n * C_OUT + 0] = a0 + lin_b[0];
        out[n * C_OUT + 1] = a1 + lin_b[1];
        out[n * C_OUT + 2] = a2 + lin_b[2];
    }
}

extern "C" void kernel_launch(void* const* d_in, const int* in_sizes, int n_in,
                              void* d_out, int out_size, void* d_ws, size_t ws_size,
                              hipStream_t stream) {
    const float* x      = (const float*)d_in[0];
    const int*   row    = (const int*)d_in[1];
    const int*   col    = (const int*)d_in[1] + EE;
    const float* eattr  = (const float*)d_in[2];
    const float* cheb_w = (const float*)d_in[3];
    const float* cheb_b = (const float*)d_in[4];
    const float* enc_w  = (const float*)d_in[5];
    const float* enc_b  = (const float*)d_in[6];
    const float* w1     = (const float*)d_in[7];
    const float* b1     = (const float*)d_in[8];
    const float* w2     = (const float*)d_in[9];
    const float* b2     = (const float*)d_in[10];
    const float* root   = (const float*)d_in[11];
    const float* conv_b = (const float*)d_in[12];
    const float* ln_g   = (const float*)d_in[13];
    const float* ln_b   = (const float*)d_in[14];
    const float* lin_w  = (const float*)d_in[15];
    const float* lin_b  = (const float*)d_in[16];

    char* base = (char*)d_ws;
    size_t off = 0;
    auto alloc = [&](size_t nbytes) {
        char* p = base + off;
        off += (nbytes + 255) / 256 * 256;
        return p;
    };
    float*  deg    = (float*)alloc(NN * 4);
    int*    cnt    = (int*)  alloc(NN * 4);
    size_t  ctl_bytes = off;
    float*  M      = (float*)alloc((size_t)L_LAYERS * H * MWM * 4);
    float*  TX     = (float*)alloc((size_t)(T_CHEB - 1) * NN * F_IN * 4);
    int*    ell_r  = (int*)  alloc((size_t)NN * MD * 4);
    float*  ell_m  = (float*)alloc((size_t)NN * MD * 4);
    float4* ell_ea = (float4*)alloc((size_t)NN * MD * 16);
    float*  bA     = (float*)alloc((size_t)NN * H * 4);   // cheb out / base ping
    float*  bB     = (float*)alloc((size_t)NN * H * 4);   // base pong
    float*  P0     = (float*)alloc((size_t)NN * PW * 4);
    float*  P1     = (float*)alloc((size_t)NN * PW * 4);
    (void)ws_size; (void)n_in; (void)in_sizes; (void)out_size;

    const int B = 256;
    auto G = [](long n, int b) { return (int)((n + b - 1) / b); };

    hipMemsetAsync(deg, 0, ctl_bytes, stream);
    k_front<<<360, B, 0, stream>>>(enc_w, enc_b, w1, b1, w2, b2, root,
                                   row, col, eattr, M, deg, cnt, ell_r, ell_m, ell_ea);

    float* T1 = (float*)TX;
    float* T2 = T1 + (size_t)NN * F_IN;
    float* T3 = T2 + (size_t)NN * F_IN;
    float* T4 = T3 + (size_t)NN * F_IN;
    k_cheb_step<<<G((long)NN * 4, B), B, 0, stream>>>(cnt, ell_r, ell_m, deg, x,  nullptr, T1, 1.f);
    k_cheb_step<<<G((long)NN * 4, B), B, 0, stream>>>(cnt, ell_r, ell_m, deg, T1, x,       T2, 2.f);
    k_cheb_step<<<G((long)NN * 4, B), B, 0, stream>>>(cnt, ell_r, ell_m, deg, T2, T1,      T3, 2.f);
    k_cheb4_out<<<G(NN, 64), B, 0, stream>>>(cnt, ell_r, ell_m, deg, x, T1, T2, T3, T4,
                                             cheb_w, cheb_b, bA);

    // layers: li=0 reads bA as v (no gather/LN), writes P0 + bB.
    // li odd reads (bB, P_{li-1}) writes bA; li even (>0) reads bA writes bB.
    float* Pbuf[2] = { P0, P1 };
    for (int li = 0; li < L_LAYERS; ++li) {
        const float* basePrev = (li & 1) ? bB : bA;   // li=0 unused (mode 0)
        float* baseOut        = (li & 1) ? bA : bB;
        k_layer<<<GPAD, B, 0, stream>>>(
            basePrev, Pbuf[(li + 1) & 1], bA,
            cnt, ell_r, ell_ea,
            M + (size_t)li * H * MWM, conv_b + li * H, ln_g + li * H, ln_b + li * H,
            Pbuf[li & 1], baseOut, li > 0 ? 1 : 0);
    }

    // after layer9 (odd): base9 = bA, P9 = Pbuf[1]
    k_final<<<G((long)NN * 8, B), B, 0, stream>>>(bA, Pbuf[1], cnt, ell_r, ell_ea,
                                                  ln_g, ln_b, lin_w, lin_b, (float*)d_out);
}

// Round 9
// 251.134 us; speedup vs baseline: 7.3563x; 1.3170x over previous
//
#include <hip/hip_runtime.h>

#define NN 5000
#define EE 10000
#define F_IN 16
#define F_EDGE 4
#define H 96
#define EHD 16
#define HID3 32
#define T_CHEB 5
#define L_LAYERS 10
#define C_OUT 3
#define LN_EPSF 1e-5f
#define MWM 576   // 4 attr mats + const mat + root mat (columns of fused M)
#define PW 480    // P stores the 5 edge-relevant col-blocks
#define MD 32     // ELL max in-degree (dataset max ~13)
#define BM 32     // rows per layer tile
#define NBT 157   // ceil(5000/32)
#define NW (NBT * 6)        // 942 work items
#define GPAD 944            // padded to 8*118 for XCD-chunked swizzle
#define CPX 118             // chunks per XCD
#define FRAG_PER_LAYER (6 * 6 * 6 * 64)   // half4 units per layer (jb,nt,kc,lane)

typedef float float4v __attribute__((ext_vector_type(4)));
typedef _Float16 half4v __attribute__((ext_vector_type(4)));
typedef _Float16 half8v __attribute__((ext_vector_type(8)));

#if __has_builtin(__builtin_amdgcn_mfma_f32_16x16x16f16)
  #define HAVE_MFMA16 1
  #define MFMA16(a, b, c) __builtin_amdgcn_mfma_f32_16x16x16f16((a), (b), (c), 0, 0, 0)
#elif __has_builtin(__builtin_amdgcn_mfma_f32_16x16x16_f16)
  #define HAVE_MFMA16 1
  #define MFMA16(a, b, c) __builtin_amdgcn_mfma_f32_16x16x16_f16((a), (b), (c), 0, 0, 0)
#else
  #define HAVE_MFMA16 0
  #define MFMA32(a, b, c) __builtin_amdgcn_mfma_f32_16x16x32_f16((a), (b), (c), 0, 0, 0)
#endif

// ================= front-end: M precompute (direct to f16 B-fragments) + ELL setup ===========
// Fragment layout for v_mfma_f32_16x16x16_f16 B operand: lane = n + 16*g holds
// B[k = kc*16 + 4g + e][n] for e=0..3.  Linear: ((((i*6+jb)*6+nt)*6+kc)*64+lane)*4+e.
__global__ void k_front(const float* __restrict__ enc_w, const float* __restrict__ enc_b,
                        const float* __restrict__ w1, const float* __restrict__ b1,
                        const float* __restrict__ w2, const float* __restrict__ b2,
                        const float* __restrict__ root,
                        const int* __restrict__ row, const int* __restrict__ col,
                        const float* __restrict__ eattr,
                        _Float16* __restrict__ Mf, float* __restrict__ deg,
                        int* __restrict__ cnt, int* __restrict__ ell_r,
                        float* __restrict__ ell_m, float4* __restrict__ ell_ea) {
    const int tid = blockIdx.x * blockDim.x + threadIdx.x;
    const int NTH = gridDim.x * blockDim.x;
    for (int idx = tid; idx < L_LAYERS * H * H; idx += NTH) {
        int i = idx / (H * H);
        int m = idx % (H * H);      // m = h*96 + o  (h = K index, o = col within 96-block)
        int h = m / H, o = m % H;
        const float* w2i = w2 + (size_t)i * HID3 * H * H;
        const float* w1i = w1 + i * EHD * HID3;
        float hcol[HID3];
        #pragma unroll
        for (int k2 = 0; k2 < HID3; ++k2) hcol[k2] = w2i[(size_t)k2 * H * H + m];
        float tcol[EHD];
        #pragma unroll
        for (int ke = 0; ke < EHD; ++ke) {
            float s = 0.f;
            #pragma unroll
            for (int k2 = 0; k2 < HID3; ++k2) s += w1i[ke * HID3 + k2] * hcol[k2];
            tcol[ke] = s;
        }
        float vals[6];
        #pragma unroll
        for (int f = 0; f < F_EDGE; ++f) {
            float s = 0.f;
            #pragma unroll
            for (int ke = 0; ke < EHD; ++ke) s += enc_w[f * EHD + ke] * tcol[ke];
            vals[f] = s;
        }
        float c = b2[(size_t)i * H * H + m];
        #pragma unroll
        for (int ke = 0; ke < EHD; ++ke) c += enc_b[ke] * tcol[ke];
        #pragma unroll
        for (int k2 = 0; k2 < HID3; ++k2) c += b1[i * HID3 + k2] * hcol[k2];
        vals[4] = c;
        vals[5] = root[(size_t)i * H * H + m];
        // scatter into fragment layout
        int nt = o >> 4, n15 = o & 15;
        int kc = h >> 4, g2 = (h & 15) >> 2, e2 = h & 3;
        int lane = n15 + 16 * g2;
        #pragma unroll
        for (int jb = 0; jb < 6; ++jb) {
            size_t base = ((((size_t)i * 6 + jb) * 6 + nt) * 6 + kc) * 64 + lane;
            Mf[base * 4 + e2] = (_Float16)vals[jb];
        }
    }
    for (int e = tid; e < EE; e += NTH) {
        int r = row[e], c = col[e];
        float4 ea = *(const float4*)(eattr + e * F_EDGE);
        float m = (ea.x == 0.f && r != c) ? 1.f : 0.f;
        if (m != 0.f) atomicAdd(&deg[r], 1.f);   // integer-valued: exact
        int slot = atomicAdd(&cnt[c], 1);
        int p = c * MD + slot;
        ell_r[p] = r;
        ell_m[p] = m;
        ell_ea[p] = ea;
    }
}

// ====== Cheb step ======
__global__ void k_cheb_step(const int* __restrict__ cnt, const int* __restrict__ ell_r,
                            const float* __restrict__ ell_m, const float* __restrict__ deg,
                            const float* __restrict__ src, const float* __restrict__ prev,
                            float* __restrict__ dst, float scale) {
    int t = blockIdx.x * blockDim.x + threadIdx.x;
    if (t >= NN * 4) return;
    int c = t >> 2, q = t & 3;
    int n = cnt[c];
    const int* rp = ell_r + c * MD;
    const float* mp = ell_m + c * MD;
    float4 acc = make_float4(0.f, 0.f, 0.f, 0.f);
    for (int p = 0; p < n; ++p) {
        float m = mp[p];
        if (m == 0.f) continue;
        int r = rp[p];
        float w = rsqrtf(deg[r]);
        float4 s = *(const float4*)(src + (size_t)r * F_IN + q * 4);
        acc.x = fmaf(w, s.x, acc.x); acc.y = fmaf(w, s.y, acc.y);
        acc.z = fmaf(w, s.z, acc.z); acc.w = fmaf(w, s.w, acc.w);
    }
    float dc = deg[c];
    float f = dc > 0.f ? -scale * rsqrtf(dc) : 0.f;
    float4 o = make_float4(f * acc.x, f * acc.y, f * acc.z, f * acc.w);
    if (prev) {
        float4 pv = *(const float4*)(prev + (size_t)c * F_IN + q * 4);
        o.x -= pv.x; o.y -= pv.y; o.z -= pv.z; o.w -= pv.w;
    }
    *(float4*)(dst + (size_t)c * F_IN + q * 4) = o;
}

// ====== Cheb step 4 fused with cheb_out ======
__global__ __launch_bounds__(256) void k_cheb4_out(
        const int* __restrict__ cnt, const int* __restrict__ ell_r,
        const float* __restrict__ ell_m, const float* __restrict__ deg,
        const float* __restrict__ x, const float* __restrict__ T1,
        const float* __restrict__ T2, const float* __restrict__ T3,
        float* __restrict__ T4, const float* __restrict__ cheb_w,
        const float* __restrict__ cheb_b, float* __restrict__ hout) {
    __shared__ float wlds[T_CHEB * F_IN][H];   // 30 KB
    const int n0 = blockIdx.x * 64;
    const int t = threadIdx.x;
    for (int i = t; i < T_CHEB * F_IN * H / 4; i += 256)
        ((float4*)wlds)[i] = ((const float4*)cheb_w)[i];
    {
        int c = n0 + (t >> 2), q = t & 3;
        if (c < NN) {
            int n = cnt[c];
            const int* rp = ell_r + c * MD;
            const float* mp = ell_m + c * MD;
            float4 acc = make_float4(0.f, 0.f, 0.f, 0.f);
            for (int p = 0; p < n; ++p) {
                float m = mp[p];
                if (m == 0.f) continue;
                int r = rp[p];
                float w = rsqrtf(deg[r]);
                float4 s = *(const float4*)(T3 + (size_t)r * F_IN + q * 4);
                acc.x = fmaf(w, s.x, acc.x); acc.y = fmaf(w, s.y, acc.y);
                acc.z = fmaf(w, s.z, acc.z); acc.w = fmaf(w, s.w, acc.w);
            }
            float dc = deg[c];
            float f = dc > 0.f ? -2.f * rsqrtf(dc) : 0.f;
            float4 pv = *(const float4*)(T2 + (size_t)c * F_IN + q * 4);
            float4 o = make_float4(f * acc.x - pv.x, f * acc.y - pv.y,
                                   f * acc.z - pv.z, f * acc.w - pv.w);
            *(float4*)(T4 + (size_t)c * F_IN + q * 4) = o;
        }
    }
    __syncthreads();
    {
        int n = n0 + (t >> 2), cseg = t & 3;
        if (n >= NN) return;
        float txv[T_CHEB * F_IN];
        #pragma unroll
        for (int q = 0; q < 4; ++q) {
            *(float4*)(txv + q * 4)      = *(const float4*)(x  + (size_t)n * F_IN + q * 4);
            *(float4*)(txv + 16 + q * 4) = *(const float4*)(T1 + (size_t)n * F_IN + q * 4);
            *(float4*)(txv + 32 + q * 4) = *(const float4*)(T2 + (size_t)n * F_IN + q * 4);
            *(float4*)(txv + 48 + q * 4) = *(const float4*)(T3 + (size_t)n * F_IN + q * 4);
            *(float4*)(txv + 64 + q * 4) = *(const float4*)(T4 + (size_t)n * F_IN + q * 4);
        }
        float* hr = hout + (size_t)n * H + cseg * 24;
        #pragma unroll 4
        for (int c = 0; c < 24; ++c) {
            int o = cseg * 24 + c;
            float s = cheb_b[o];
            #pragma unroll
            for (int kf = 0; kf < T_CHEB * F_IN; ++kf)
                s = fmaf(txv[kf], wlds[kf][o], s);
            hr[c] = s;
        }
    }
}

// ====== per-layer fused: gather + LN/ReLU + MFMA GEMM (32-row x 96-col tiles) ======
// grid 944 (XCD-chunked swizzle onto 157x6 work items), 256 threads = 4 waves.
// Wave w: rows 16*(w&1).., cols 48*(w>>1).. (3 x 16-col MFMA tiles), K = 96.
__global__ __launch_bounds__(256) void k_layer(
        const float* __restrict__ basePrev, const float* __restrict__ Pprev,
        const float* __restrict__ vsrc0,
        const int* __restrict__ cnt, const int* __restrict__ ell_r,
        const float4* __restrict__ ell_ea, const _Float16* __restrict__ MfL,
        const float* __restrict__ cb, const float* __restrict__ lg,
        const float* __restrict__ lb,
        float* __restrict__ Pout, float* __restrict__ baseOut, int mode) {
    int w = (blockIdx.x & 7) * CPX + (blockIdx.x >> 3);
    if (w >= NW) return;
    const int nb = w / 6, jb = w % 6;
    const int n0 = nb * BM, j0 = jb * 96;
    const int t = threadIdx.x;

    __shared__ float vA[BM][100];    // post-LN v, row-major (12.5 KB, stride 100 dw)
    __shared__ float hgat[BM][100];  // pre-LN gathered h (residual)

    // ---- phase 1: gather + LN + ReLU -> vA ----
    {
        int r = t >> 3, l8 = t & 7;
        int gn = n0 + r, o = l8 * 12;
        float xv[12] = {0,0,0,0,0,0,0,0,0,0,0,0};
        if (gn < NN) {
            if (mode) {
                const float* bp = basePrev + (size_t)gn * H + o;
                *(float4*)(xv + 0) = *(const float4*)(bp + 0);
                *(float4*)(xv + 4) = *(const float4*)(bp + 4);
                *(float4*)(xv + 8) = *(const float4*)(bp + 8);
                int nc = cnt[gn];
                const int* rp = ell_r + gn * MD;
                const float4* eap = ell_ea + gn * MD;
                for (int p = 0; p < nc; ++p) {
                    int r2 = rp[p];
                    float4 ea = eap[p];
                    const float* pb = Pprev + (size_t)r2 * PW + o;
                    #pragma unroll
                    for (int q = 0; q < 3; ++q) {
                        float4 c0 = *(const float4*)(pb + 384 + q * 4);
                        xv[q*4+0] += c0.x; xv[q*4+1] += c0.y;
                        xv[q*4+2] += c0.z; xv[q*4+3] += c0.w;
                    }
                    const float cf[4] = {ea.x, ea.y, ea.z, ea.w};
                    #pragma unroll
                    for (int f = 0; f < 4; ++f) {
                        #pragma unroll
                        for (int q = 0; q < 3; ++q) {
                            float4 p0 = *(const float4*)(pb + f * 96 + q * 4);
                            xv[q*4+0] = fmaf(cf[f], p0.x, xv[q*4+0]);
                            xv[q*4+1] = fmaf(cf[f], p0.y, xv[q*4+1]);
                            xv[q*4+2] = fmaf(cf[f], p0.z, xv[q*4+2]);
                            xv[q*4+3] = fmaf(cf[f], p0.w, xv[q*4+3]);
                        }
                    }
                }
            } else {
                const float* bp = vsrc0 + (size_t)gn * H + o;
                *(float4*)(xv + 0) = *(const float4*)(bp + 0);
                *(float4*)(xv + 4) = *(const float4*)(bp + 4);
                *(float4*)(xv + 8) = *(const float4*)(bp + 8);
            }
        }
        if (mode) {
            *(float4*)&hgat[r][o + 0] = *(const float4*)(xv + 0);
            *(float4*)&hgat[r][o + 4] = *(const float4*)(xv + 4);
            *(float4*)&hgat[r][o + 8] = *(const float4*)(xv + 8);
            float s = 0.f;
            #pragma unroll
            for (int i = 0; i < 12; ++i) s += xv[i];
            s += __shfl_xor(s, 1); s += __shfl_xor(s, 2); s += __shfl_xor(s, 4);
            float mu = s * (1.0f / H);
            float vv = 0.f;
            #pragma unroll
            for (int i = 0; i < 12; ++i) { float d = xv[i] - mu; vv += d * d; }
            vv += __shfl_xor(vv, 1); vv += __shfl_xor(vv, 2); vv += __shfl_xor(vv, 4);
            float is = rsqrtf(vv * (1.0f / H) + LN_EPSF);
            const float* gp = lg + o;
            const float* bp2 = lb + o;
            #pragma unroll
            for (int i = 0; i < 12; ++i)
                xv[i] = fmaxf(fmaf((xv[i] - mu) * is, gp[i], bp2[i]), 0.f);
        }
        *(float4*)&vA[r][o + 0] = *(const float4*)(xv + 0);
        *(float4*)&vA[r][o + 4] = *(const float4*)(xv + 4);
        *(float4*)&vA[r][o + 8] = *(const float4*)(xv + 8);
    }
    __syncthreads();

    // ---- phase 2: MFMA GEMM ----
    const int wid = t >> 6, l = t & 63;
    const int R0 = (wid & 1) * 16;
    const int NT0 = (wid >> 1) * 3;     // first 16-col tile (0..5)
    const int n15 = l & 15, g = l >> 4;
    const int m = R0 + n15;
    const half4v* Mf4 = (const half4v*)MfL;

    float4v acc[3] = {};
#if HAVE_MFMA16
    half4v afr[6];
    #pragma unroll
    for (int kc = 0; kc < 6; ++kc) {
        const float* ap = &vA[m][kc * 16 + 4 * g];
        half4v a;
        a[0] = (_Float16)ap[0]; a[1] = (_Float16)ap[1];
        a[2] = (_Float16)ap[2]; a[3] = (_Float16)ap[3];
        afr[kc] = a;
    }
    #pragma unroll
    for (int nt = 0; nt < 3; ++nt) {
        int ntg = NT0 + nt;
        const half4v* Bp = Mf4 + ((jb * 6 + ntg) * 6) * 64 + l;
        #pragma unroll
        for (int kc = 0; kc < 6; ++kc)
            acc[nt] = MFMA16(afr[kc], Bp[kc * 64], acc[nt]);
    }
#else
    // fallback: 16x16x32 with two-half K layout (elems 0-3: k=4g+e, 4-7: k=16+4g+e)
    half8v afr[3];
    #pragma unroll
    for (int kc = 0; kc < 3; ++kc) {
        const float* ap0 = &vA[m][kc * 32 + 4 * g];
        const float* ap1 = &vA[m][kc * 32 + 16 + 4 * g];
        half8v a;
        #pragma unroll
        for (int e = 0; e < 4; ++e) { a[e] = (_Float16)ap0[e]; a[4 + e] = (_Float16)ap1[e]; }
        afr[kc] = a;
    }
    #pragma unroll
    for (int nt = 0; nt < 3; ++nt) {
        int ntg = NT0 + nt;
        #pragma unroll
        for (int kc = 0; kc < 3; ++kc) {
            half4v b0 = Mf4[((jb * 6 + ntg) * 6 + 2 * kc) * 64 + l];
            half4v b1 = Mf4[((jb * 6 + ntg) * 6 + 2 * kc + 1) * 64 + l];
            half8v b;
            #pragma unroll
            for (int e = 0; e < 4; ++e) { b[e] = b0[e]; b[4 + e] = b1[e]; }
            acc[nt] = MFMA32(afr[kc], b, acc[nt]);
        }
    }
#endif

    // ---- epilogue: D[row = R0+4g+e][col = ntg*16+n15] ----
    #pragma unroll
    for (int nt = 0; nt < 3; ++nt) {
        int cc = (NT0 + nt) * 16 + n15;          // 0..95 within col-block
        #pragma unroll
        for (int e = 0; e < 4; ++e) {
            int lr = R0 + 4 * g + e;
            int gn = n0 + lr;
            if (gn >= NN) continue;
            float val = acc[nt][e];
            if (jb < 5) {
                Pout[(size_t)gn * PW + j0 + cc] = val;
            } else {
                baseOut[(size_t)gn * H + cc] = val + cb[cc] + (mode ? hgat[lr][cc] : 0.f);
            }
        }
    }
}

// ====== final: gather h9 + LN(params0) + relu + linear(96->3) ======
__global__ void k_final(const float* __restrict__ base, const float* __restrict__ P,
                        const int* __restrict__ cnt, const int* __restrict__ ell_r,
                        const float4* __restrict__ ell_ea,
                        const float* __restrict__ g, const float* __restrict__ b,
                        const float* __restrict__ lin_w, const float* __restrict__ lin_b,
                        float* __restrict__ out) {
    int tid = blockIdx.x * blockDim.x + threadIdx.x;
    int n = tid >> 3, l8 = tid & 7;
    if (n >= NN) return;
    int o = l8 * 12;
    float xv[12];
    {
        const float* bp = base + (size_t)n * H + o;
        *(float4*)(xv + 0) = *(const float4*)(bp + 0);
        *(float4*)(xv + 4) = *(const float4*)(bp + 4);
        *(float4*)(xv + 8) = *(const float4*)(bp + 8);
        int nc = cnt[n];
        const int* rp = ell_r + n * MD;
        const float4* eap = ell_ea + n * MD;
        for (int p = 0; p < nc; ++p) {
            int r2 = rp[p];
            float4 ea = eap[p];
            const float* pb = P + (size_t)r2 * PW + o;
            const float cf[4] = {ea.x, ea.y, ea.z, ea.w};
            #pragma unroll
            for (int q = 0; q < 3; ++q) {
                float4 c0 = *(const float4*)(pb + 384 + q * 4);
                xv[q*4+0] += c0.x; xv[q*4+1] += c0.y;
                xv[q*4+2] += c0.z; xv[q*4+3] += c0.w;
                #pragma unroll
                for (int f = 0; f < 4; ++f) {
                    float4 p0 = *(const float4*)(pb + f * 96 + q * 4);
                    xv[q*4+0] = fmaf(cf[f], p0.x, xv[q*4+0]);
                    xv[q*4+1] = fmaf(cf[f], p0.y, xv[q*4+1]);
                    xv[q*4+2] = fmaf(cf[f], p0.z, xv[q*4+2]);
                    xv[q*4+3] = fmaf(cf[f], p0.w, xv[q*4+3]);
                }
            }
        }
    }
    float s = 0.f;
    #pragma unroll
    for (int i = 0; i < 12; ++i) s += xv[i];
    s += __shfl_xor(s, 1); s += __shfl_xor(s, 2); s += __shfl_xor(s, 4);
    float mu = s * (1.0f / H);
    float vv = 0.f;
    #pragma unroll
    for (int i = 0; i < 12; ++i) { float d = xv[i] - mu; vv += d * d; }
    vv += __shfl_xor(vv, 1); vv += __shfl_xor(vv, 2); vv += __shfl_xor(vv, 4);
    float is = rsqrtf(vv * (1.0f / H) + LN_EPSF);
    const float* gp = g + o;
    const float* bp = b + o;
    float a0 = 0.f, a1 = 0.f, a2 = 0.f;
    #pragma unroll
    for (int i = 0; i < 12; ++i) {
        float tt = fmaxf(fmaf((xv[i] - mu) * is, gp[i], bp[i]), 0.f);
        int oo = o + i;
        a0 = fmaf(tt, lin_w[oo * C_OUT + 0], a0);
        a1 = fmaf(tt, lin_w[oo * C_OUT + 1], a1);
        a2 = fmaf(tt, lin_w[oo * C_OUT + 2], a2);
    }
    a0 += __shfl_xor(a0, 1); a0 += __shfl_xor(a0, 2); a0 += __shfl_xor(a0, 4);
    a1 += __shfl_xor(a1, 1); a1 += __shfl_xor(a1, 2); a1 += __shfl_xor(a1, 4);
    a2 += __shfl_xor(a2, 1); a2 += __shfl_xor(a2, 2); a2 += __shfl_xor(a2, 4);
    if (l8 == 0) {
        out[n * C_OUT + 0] = a0 + lin_b[0];
        out[n * C_OUT + 1] = a1 + lin_b[1];
        out[n * C_OUT + 2] = a2 + lin_b[2];
    }
}

extern "C" void kernel_launch(void* const* d_in, const int* in_sizes, int n_in,
                              void* d_out, int out_size, void* d_ws, size_t ws_size,
                              hipStream_t stream) {
    const float* x      = (const float*)d_in[0];
    const int*   row    = (const int*)d_in[1];
    const int*   col    = (const int*)d_in[1] + EE;
    const float* eattr  = (const float*)d_in[2];
    const float* cheb_w = (const float*)d_in[3];
    const float* cheb_b = (const float*)d_in[4];
    const float* enc_w  = (const float*)d_in[5];
    const float* enc_b  = (const float*)d_in[6];
    const float* w1     = (const float*)d_in[7];
    const float* b1     = (const float*)d_in[8];
    const float* w2     = (const float*)d_in[9];
    const float* b2     = (const float*)d_in[10];
    const float* root   = (const float*)d_in[11];
    const float* conv_b = (const float*)d_in[12];
    const float* ln_g   = (const float*)d_in[13];
    const float* ln_b   = (const float*)d_in[14];
    const float* lin_w  = (const float*)d_in[15];
    const float* lin_b  = (const float*)d_in[16];

    char* base = (char*)d_ws;
    size_t off = 0;
    auto alloc = [&](size_t nbytes) {
        char* p = base + off;
        off += (nbytes + 255) / 256 * 256;
        return p;
    };
    float*    deg    = (float*)alloc(NN * 4);
    int*      cnt    = (int*)  alloc(NN * 4);
    size_t    ctl_bytes = off;
    _Float16* Mfrag  = (_Float16*)alloc((size_t)L_LAYERS * FRAG_PER_LAYER * 4 * 2);
    float*    TX     = (float*)alloc((size_t)(T_CHEB - 1) * NN * F_IN * 4);
    int*      ell_r  = (int*)  alloc((size_t)NN * MD * 4);
    float*    ell_m  = (float*)alloc((size_t)NN * MD * 4);
    float4*   ell_ea = (float4*)alloc((size_t)NN * MD * 16);
    float*    bA     = (float*)alloc((size_t)NN * H * 4);   // cheb out / base ping
    float*    bB     = (float*)alloc((size_t)NN * H * 4);   // base pong
    float*    P0     = (float*)alloc((size_t)NN * PW * 4);
    float*    P1     = (float*)alloc((size_t)NN * PW * 4);
    (void)ws_size; (void)n_in; (void)in_sizes; (void)out_size;

    const int B = 256;
    auto G = [](long n, int b) { return (int)((n + b - 1) / b); };

    hipMemsetAsync(deg, 0, ctl_bytes, stream);
    k_front<<<360, B, 0, stream>>>(enc_w, enc_b, w1, b1, w2, b2, root,
                                   row, col, eattr, Mfrag, deg, cnt, ell_r, ell_m, ell_ea);

    float* T1 = (float*)TX;
    float* T2 = T1 + (size_t)NN * F_IN;
    float* T3 = T2 + (size_t)NN * F_IN;
    float* T4 = T3 + (size_t)NN * F_IN;
    k_cheb_step<<<G((long)NN * 4, B), B, 0, stream>>>(cnt, ell_r, ell_m, deg, x,  nullptr, T1, 1.f);
    k_cheb_step<<<G((long)NN * 4, B), B, 0, stream>>>(cnt, ell_r, ell_m, deg, T1, x,       T2, 2.f);
    k_cheb_step<<<G((long)NN * 4, B), B, 0, stream>>>(cnt, ell_r, ell_m, deg, T2, T1,      T3, 2.f);
    k_cheb4_out<<<G(NN, 64), B, 0, stream>>>(cnt, ell_r, ell_m, deg, x, T1, T2, T3, T4,
                                             cheb_w, cheb_b, bA);

    float* Pbuf[2] = { P0, P1 };
    for (int li = 0; li < L_LAYERS; ++li) {
        const float* basePrev = (li & 1) ? bB : bA;   // li=0 unused (mode 0)
        float* baseOut        = (li & 1) ? bA : bB;
        k_layer<<<GPAD, B, 0, stream>>>(
            basePrev, Pbuf[(li + 1) & 1], bA,
            cnt, ell_r, ell_ea,
            Mfrag + (size_t)li * FRAG_PER_LAYER * 4,
            conv_b + li * H, ln_g + li * H, ln_b + li * H,
            Pbuf[li & 1], baseOut, li > 0 ? 1 : 0);
    }

    // after layer9 (odd): base9 = bA, P9 = Pbuf[1]
    k_final<<<G((long)NN * 8, B), B, 0, stream>>>(bA, Pbuf[1], cnt, ell_r, ell_ea,
                                                  ln_g, ln_b, lin_w, lin_b, (float*)d_out);
}

// Round 10
// 168.876 us; speedup vs baseline: 10.9395x; 1.4871x over previous
//
#include <hip/hip_runtime.h>

#define NN 5000
#define EE 10000
#define F_IN 16
#define F_EDGE 4
#define H 96
#define EHD 16
#define HID3 32
#define T_CHEB 5
#define L_LAYERS 10
#define C_OUT 3
#define LN_EPSF 1e-5f
#define KW 576    // stacked K: 4 attr mats + const mat + root (rows of M_stack)
#define MD 32     // ELL max in-degree (dataset max ~13)
#define BM2 16    // rows per layer block
#define NBT2 313  // ceil(5000/16)
#define KC_N 36   // K chunks of 16
#define FRAG_PER_LAYER (6 * KC_N * 64)   // half4 units per layer (nt,kc,lane)

typedef float float4v __attribute__((ext_vector_type(4)));
typedef _Float16 half4v __attribute__((ext_vector_type(4)));
typedef _Float16 half8v __attribute__((ext_vector_type(8)));

#if __has_builtin(__builtin_amdgcn_mfma_f32_16x16x16f16)
  #define HAVE_MFMA16 1
  #define MFMA16(a, b, c) __builtin_amdgcn_mfma_f32_16x16x16f16((a), (b), (c), 0, 0, 0)
#elif __has_builtin(__builtin_amdgcn_mfma_f32_16x16x16_f16)
  #define HAVE_MFMA16 1
  #define MFMA16(a, b, c) __builtin_amdgcn_mfma_f32_16x16x16_f16((a), (b), (c), 0, 0, 0)
#else
  #define HAVE_MFMA16 0
  #define MFMA32(a, b, c) __builtin_amdgcn_mfma_f32_16x16x32_f16((a), (b), (c), 0, 0, 0)
#endif

// ========= front-end: M_stack (576x96) to f16 B-fragments + ELL setup =========
// B-frag: lane = n15 + 16*g holds B[k = kc*16 + 4g + e][col = nt*16 + n15], e=0..3
// Linear half index: (((i*6 + nt)*36 + kc)*64 + lane)*4 + e
__global__ void k_front(const float* __restrict__ enc_w, const float* __restrict__ enc_b,
                        const float* __restrict__ w1, const float* __restrict__ b1,
                        const float* __restrict__ w2, const float* __restrict__ b2,
                        const float* __restrict__ root,
                        const int* __restrict__ row, const int* __restrict__ col,
                        const float* __restrict__ eattr,
                        _Float16* __restrict__ Mf, float* __restrict__ deg,
                        int* __restrict__ cnt, int* __restrict__ ell_r,
                        float* __restrict__ ell_m, float4* __restrict__ ell_ea) {
    const int tid = blockIdx.x * blockDim.x + threadIdx.x;
    const int NTH = gridDim.x * blockDim.x;
    for (int idx = tid; idx < L_LAYERS * H * H; idx += NTH) {
        int i = idx / (H * H);
        int m = idx % (H * H);      // m = h*96 + o   (h: inner K row, o: output col)
        int h = m / H, o = m % H;
        const float* w2i = w2 + (size_t)i * HID3 * H * H;
        const float* w1i = w1 + i * EHD * HID3;
        float hcol[HID3];
        #pragma unroll
        for (int k2 = 0; k2 < HID3; ++k2) hcol[k2] = w2i[(size_t)k2 * H * H + m];
        float tcol[EHD];
        #pragma unroll
        for (int ke = 0; ke < EHD; ++ke) {
            float s = 0.f;
            #pragma unroll
            for (int k2 = 0; k2 < HID3; ++k2) s += w1i[ke * HID3 + k2] * hcol[k2];
            tcol[ke] = s;
        }
        float vals[6];
        #pragma unroll
        for (int f = 0; f < F_EDGE; ++f) {
            float s = 0.f;
            #pragma unroll
            for (int ke = 0; ke < EHD; ++ke) s += enc_w[f * EHD + ke] * tcol[ke];
            vals[f] = s;
        }
        float c = b2[(size_t)i * H * H + m];
        #pragma unroll
        for (int ke = 0; ke < EHD; ++ke) c += enc_b[ke] * tcol[ke];
        #pragma unroll
        for (int k2 = 0; k2 < HID3; ++k2) c += b1[i * HID3 + k2] * hcol[k2];
        vals[4] = c;
        vals[5] = root[(size_t)i * H * H + m];
        int nt = o >> 4, n15 = o & 15;
        #pragma unroll
        for (int f = 0; f < 6; ++f) {
            int k = f * 96 + h;                      // stacked K index
            int kc = k >> 4, g2 = (k & 15) >> 2, e2 = k & 3;
            int lane = n15 + 16 * g2;
            Mf[((((size_t)i * 6 + nt) * KC_N + kc) * 64 + lane) * 4 + e2] = (_Float16)vals[f];
        }
    }
    for (int e = tid; e < EE; e += NTH) {
        int r = row[e], c = col[e];
        float4 ea = *(const float4*)(eattr + e * F_EDGE);
        float m = (ea.x == 0.f && r != c) ? 1.f : 0.f;
        if (m != 0.f) atomicAdd(&deg[r], 1.f);   // integer-valued: exact
        int slot = atomicAdd(&cnt[c], 1);
        int p = c * MD + slot;
        ell_r[p] = r;
        ell_m[p] = m;
        ell_ea[p] = ea;
    }
}

// ====== Cheb step ======
__global__ void k_cheb_step(const int* __restrict__ cnt, const int* __restrict__ ell_r,
                            const float* __restrict__ ell_m, const float* __restrict__ deg,
                            const float* __restrict__ src, const float* __restrict__ prev,
                            float* __restrict__ dst, float scale) {
    int t = blockIdx.x * blockDim.x + threadIdx.x;
    if (t >= NN * 4) return;
    int c = t >> 2, q = t & 3;
    int n = cnt[c];
    const int* rp = ell_r + c * MD;
    const float* mp = ell_m + c * MD;
    float4 acc = make_float4(0.f, 0.f, 0.f, 0.f);
    for (int p = 0; p < n; ++p) {
        float m = mp[p];
        if (m == 0.f) continue;
        int r = rp[p];
        float w = rsqrtf(deg[r]);
        float4 s = *(const float4*)(src + (size_t)r * F_IN + q * 4);
        acc.x = fmaf(w, s.x, acc.x); acc.y = fmaf(w, s.y, acc.y);
        acc.z = fmaf(w, s.z, acc.z); acc.w = fmaf(w, s.w, acc.w);
    }
    float dc = deg[c];
    float f = dc > 0.f ? -scale * rsqrtf(dc) : 0.f;
    float4 o = make_float4(f * acc.x, f * acc.y, f * acc.z, f * acc.w);
    if (prev) {
        float4 pv = *(const float4*)(prev + (size_t)c * F_IN + q * 4);
        o.x -= pv.x; o.y -= pv.y; o.z -= pv.z; o.w -= pv.w;
    }
    *(float4*)(dst + (size_t)c * F_IN + q * 4) = o;
}

// ====== Cheb step 4 fused with cheb_out -> v0 (f16 row-major) ======
__global__ __launch_bounds__(256) void k_cheb4_out(
        const int* __restrict__ cnt, const int* __restrict__ ell_r,
        const float* __restrict__ ell_m, const float* __restrict__ deg,
        const float* __restrict__ x, const float* __restrict__ T1,
        const float* __restrict__ T2, const float* __restrict__ T3,
        float* __restrict__ T4, const float* __restrict__ cheb_w,
        const float* __restrict__ cheb_b, _Float16* __restrict__ vout) {
    __shared__ float wlds[T_CHEB * F_IN][H];   // 30 KB
    const int n0 = blockIdx.x * 64;
    const int t = threadIdx.x;
    for (int i = t; i < T_CHEB * F_IN * H / 4; i += 256)
        ((float4*)wlds)[i] = ((const float4*)cheb_w)[i];
    {
        int c = n0 + (t >> 2), q = t & 3;
        if (c < NN) {
            int n = cnt[c];
            const int* rp = ell_r + c * MD;
            const float* mp = ell_m + c * MD;
            float4 acc = make_float4(0.f, 0.f, 0.f, 0.f);
            for (int p = 0; p < n; ++p) {
                float m = mp[p];
                if (m == 0.f) continue;
                int r = rp[p];
                float w = rsqrtf(deg[r]);
                float4 s = *(const float4*)(T3 + (size_t)r * F_IN + q * 4);
                acc.x = fmaf(w, s.x, acc.x); acc.y = fmaf(w, s.y, acc.y);
                acc.z = fmaf(w, s.z, acc.z); acc.w = fmaf(w, s.w, acc.w);
            }
            float dc = deg[c];
            float f = dc > 0.f ? -2.f * rsqrtf(dc) : 0.f;
            float4 pv = *(const float4*)(T2 + (size_t)c * F_IN + q * 4);
            float4 o = make_float4(f * acc.x - pv.x, f * acc.y - pv.y,
                                   f * acc.z - pv.z, f * acc.w - pv.w);
            *(float4*)(T4 + (size_t)c * F_IN + q * 4) = o;
        }
    }
    __syncthreads();
    {
        int n = n0 + (t >> 2), cseg = t & 3;
        if (n >= NN) return;
        float txv[T_CHEB * F_IN];
        #pragma unroll
        for (int q = 0; q < 4; ++q) {
            *(float4*)(txv + q * 4)      = *(const float4*)(x  + (size_t)n * F_IN + q * 4);
            *(float4*)(txv + 16 + q * 4) = *(const float4*)(T1 + (size_t)n * F_IN + q * 4);
            *(float4*)(txv + 32 + q * 4) = *(const float4*)(T2 + (size_t)n * F_IN + q * 4);
            *(float4*)(txv + 48 + q * 4) = *(const float4*)(T3 + (size_t)n * F_IN + q * 4);
            *(float4*)(txv + 64 + q * 4) = *(const float4*)(T4 + (size_t)n * F_IN + q * 4);
        }
        _Float16* vr = vout + (size_t)n * H + cseg * 24;
        #pragma unroll 4
        for (int c = 0; c < 24; ++c) {
            int o = cseg * 24 + c;
            float s = cheb_b[o];
            #pragma unroll
            for (int kf = 0; kf < T_CHEB * F_IN; ++kf)
                s = fmaf(txv[kf], wlds[kf][o], s);
            vr[c] = (_Float16)s;
        }
    }
}

// ====== per-layer: z-aggregate (f16) + MFMA (16 x 96, K=576) + LN epilogue ======
// grid 313 x 128 threads (2 waves).  z[c] = [Σea_f·v[r] (4x96) | Σv[r] | v[c]]
// h_next = z @ M_stack + cb (+ hres);  v_next = relu(LN(h_next)) (or lin head if last)
__global__ __launch_bounds__(128) void k_layer(
        const _Float16* __restrict__ vcur, const float* __restrict__ hres,
        const int* __restrict__ cnt, const int* __restrict__ ell_r,
        const float4* __restrict__ ell_ea, const _Float16* __restrict__ MfL,
        const float* __restrict__ cb, const float* __restrict__ lg,
        const float* __restrict__ lb, const float* __restrict__ lin_w,
        const float* __restrict__ lin_b,
        float* __restrict__ hnext, _Float16* __restrict__ vnext,
        float* __restrict__ outp, int isLast) {
    __shared__ _Float16 zs[BM2][584];   // 18.7 KB, pad -> 2-way banks on frag reads
    __shared__ float ho[BM2][100];      // 6.4 KB
    const int n0 = blockIdx.x * BM2;
    const int t = threadIdx.x;

    // ---- phase 1: build z rows ----
    {
        int r = t >> 3, l8 = t & 7;
        int gn = n0 + r, c0 = l8 * 12;
        float acc[5][12] = {};
        _Float16 selfv[12];
        #pragma unroll
        for (int j = 0; j < 12; ++j) selfv[j] = (_Float16)0.f;
        if (gn < NN) {
            const _Float16* sv = vcur + (size_t)gn * H + c0;
            *(half8v*)(selfv) = *(const half8v*)(sv);
            *(half4v*)(selfv + 8) = *(const half4v*)(sv + 8);
            int nc = cnt[gn];
            const int* rp = ell_r + gn * MD;
            const float4* eap = ell_ea + gn * MD;
            for (int p = 0; p < nc; ++p) {
                int r2 = rp[p];
                float4 ea = eap[p];
                const _Float16* vv = vcur + (size_t)r2 * H + c0;
                half8v v8 = *(const half8v*)vv;
                half4v v4 = *(const half4v*)(vv + 8);
                float vf[12];
                #pragma unroll
                for (int j = 0; j < 8; ++j) vf[j] = (float)v8[j];
                #pragma unroll
                for (int j = 0; j < 4; ++j) vf[8 + j] = (float)v4[j];
                const float cf[4] = {ea.x, ea.y, ea.z, ea.w};
                #pragma unroll
                for (int f = 0; f < 4; ++f)
                    #pragma unroll
                    for (int j = 0; j < 12; ++j)
                        acc[f][j] = fmaf(cf[f], vf[j], acc[f][j]);
                #pragma unroll
                for (int j = 0; j < 12; ++j) acc[4][j] += vf[j];
            }
        }
        #pragma unroll
        for (int f = 0; f < 5; ++f)
            #pragma unroll
            for (int j = 0; j < 12; ++j)
                zs[r][f * 96 + c0 + j] = (_Float16)acc[f][j];
        #pragma unroll
        for (int j = 0; j < 12; ++j) zs[r][480 + c0 + j] = selfv[j];
    }
    __syncthreads();

    // ---- phase 2: MFMA, wave wid does col-tiles 3*wid..3*wid+2 ----
    const int wid = t >> 6, l = t & 63;
    const int n15 = l & 15, g = l >> 4;
    const half4v* Mf4 = (const half4v*)MfL;
    float4v acc3[3] = {};
#if HAVE_MFMA16
    for (int kc0 = 0; kc0 < KC_N; kc0 += 12) {
        half4v af[12];
        #pragma unroll
        for (int kk = 0; kk < 12; ++kk)
            af[kk] = *(const half4v*)&zs[n15][(kc0 + kk) * 16 + 4 * g];
        #pragma unroll
        for (int j = 0; j < 3; ++j) {
            int nt = wid * 3 + j;
            const half4v* Bp = Mf4 + ((size_t)nt * KC_N + kc0) * 64 + l;
            #pragma unroll
            for (int kk = 0; kk < 12; ++kk)
                acc3[j] = MFMA16(af[kk], Bp[kk * 64], acc3[j]);
        }
    }
#else
    for (int kc0 = 0; kc0 < KC_N; kc0 += 12) {
        half8v af[6];
        #pragma unroll
        for (int kk = 0; kk < 6; ++kk) {
            half4v a0 = *(const half4v*)&zs[n15][(kc0 + 2 * kk) * 16 + 4 * g];
            half4v a1 = *(const half4v*)&zs[n15][(kc0 + 2 * kk + 1) * 16 + 4 * g];
            half8v a;
            #pragma unroll
            for (int e = 0; e < 4; ++e) { a[e] = a0[e]; a[4 + e] = a1[e]; }
            af[kk] = a;
        }
        #pragma unroll
        for (int j = 0; j < 3; ++j) {
            int nt = wid * 3 + j;
            const half4v* Bp = Mf4 + ((size_t)nt * KC_N + kc0) * 64 + l;
            #pragma unroll
            for (int kk = 0; kk < 6; ++kk) {
                half4v b0 = Bp[(2 * kk) * 64];
                half4v b1 = Bp[(2 * kk + 1) * 64];
                half8v b;
                #pragma unroll
                for (int e = 0; e < 4; ++e) { b[e] = b0[e]; b[4 + e] = b1[e]; }
                acc3[j] = MFMA32(af[kk], b, acc3[j]);
            }
        }
    }
#endif
    // D[row = 4g+e][col = nt*16+n15] -> LDS (+conv_b)
    #pragma unroll
    for (int j = 0; j < 3; ++j) {
        int cc = (wid * 3 + j) * 16 + n15;
        #pragma unroll
        for (int e = 0; e < 4; ++e)
            ho[4 * g + e][cc] = acc3[j][e] + cb[cc];
    }
    __syncthreads();

    // ---- phase 3: residual + LN + ReLU epilogue ----
    {
        int r = t >> 3, l8 = t & 7;
        int gn = n0 + r, c0 = l8 * 12;
        if (gn >= NN) return;
        float hv[12];
        #pragma unroll
        for (int j = 0; j < 12; ++j) hv[j] = ho[r][c0 + j];
        if (hres) {
            const float* rp = hres + (size_t)gn * H + c0;
            #pragma unroll
            for (int j = 0; j < 12; j += 4) {
                float4 rv = *(const float4*)(rp + j);
                hv[j] += rv.x; hv[j + 1] += rv.y; hv[j + 2] += rv.z; hv[j + 3] += rv.w;
            }
        }
        if (!isLast) {
            float* hp = hnext + (size_t)gn * H + c0;
            #pragma unroll
            for (int j = 0; j < 12; j += 4)
                *(float4*)(hp + j) = make_float4(hv[j], hv[j + 1], hv[j + 2], hv[j + 3]);
        }
        float s = 0.f;
        #pragma unroll
        for (int j = 0; j < 12; ++j) s += hv[j];
        s += __shfl_xor(s, 1); s += __shfl_xor(s, 2); s += __shfl_xor(s, 4);
        float mu = s * (1.0f / H);
        float vv = 0.f;
        #pragma unroll
        for (int j = 0; j < 12; ++j) { float d = hv[j] - mu; vv += d * d; }
        vv += __shfl_xor(vv, 1); vv += __shfl_xor(vv, 2); vv += __shfl_xor(vv, 4);
        float is = rsqrtf(vv * (1.0f / H) + LN_EPSF);
        const float* gp = lg + c0;
        const float* bp = lb + c0;
        float yv[12];
        #pragma unroll
        for (int j = 0; j < 12; ++j)
            yv[j] = fmaxf(fmaf((hv[j] - mu) * is, gp[j], bp[j]), 0.f);
        if (!isLast) {
            _Float16 yh[12];
            #pragma unroll
            for (int j = 0; j < 12; ++j) yh[j] = (_Float16)yv[j];
            _Float16* vp = vnext + (size_t)gn * H + c0;
            *(half8v*)vp = *(const half8v*)yh;
            *(half4v*)(vp + 8) = *(const half4v*)(yh + 8);
        } else {
            float a0 = 0.f, a1 = 0.f, a2 = 0.f;
            #pragma unroll
            for (int j = 0; j < 12; ++j) {
                int oo = c0 + j;
                a0 = fmaf(yv[j], lin_w[oo * C_OUT + 0], a0);
                a1 = fmaf(yv[j], lin_w[oo * C_OUT + 1], a1);
                a2 = fmaf(yv[j], lin_w[oo * C_OUT + 2], a2);
            }
            a0 += __shfl_xor(a0, 1); a0 += __shfl_xor(a0, 2); a0 += __shfl_xor(a0, 4);
            a1 += __shfl_xor(a1, 1); a1 += __shfl_xor(a1, 2); a1 += __shfl_xor(a1, 4);
            a2 += __shfl_xor(a2, 1); a2 += __shfl_xor(a2, 2); a2 += __shfl_xor(a2, 4);
            if (l8 == 0) {
                outp[gn * C_OUT + 0] = a0 + lin_b[0];
                outp[gn * C_OUT + 1] = a1 + lin_b[1];
                outp[gn * C_OUT + 2] = a2 + lin_b[2];
            }
        }
    }
}

extern "C" void kernel_launch(void* const* d_in, const int* in_sizes, int n_in,
                              void* d_out, int out_size, void* d_ws, size_t ws_size,
                              hipStream_t stream) {
    const float* x      = (const float*)d_in[0];
    const int*   row    = (const int*)d_in[1];
    const int*   col    = (const int*)d_in[1] + EE;
    const float* eattr  = (const float*)d_in[2];
    const float* cheb_w = (const float*)d_in[3];
    const float* cheb_b = (const float*)d_in[4];
    const float* enc_w  = (const float*)d_in[5];
    const float* enc_b  = (const float*)d_in[6];
    const float* w1     = (const float*)d_in[7];
    const float* b1     = (const float*)d_in[8];
    const float* w2     = (const float*)d_in[9];
    const float* b2     = (const float*)d_in[10];
    const float* root   = (const float*)d_in[11];
    const float* conv_b = (const float*)d_in[12];
    const float* ln_g   = (const float*)d_in[13];
    const float* ln_b   = (const float*)d_in[14];
    const float* lin_w  = (const float*)d_in[15];
    const float* lin_b  = (const float*)d_in[16];

    char* base = (char*)d_ws;
    size_t off = 0;
    auto alloc = [&](size_t nbytes) {
        char* p = base + off;
        off += (nbytes + 255) / 256 * 256;
        return p;
    };
    float*    deg    = (float*)alloc(NN * 4);
    int*      cnt    = (int*)  alloc(NN * 4);
    size_t    ctl_bytes = off;
    _Float16* Mfrag  = (_Float16*)alloc((size_t)L_LAYERS * FRAG_PER_LAYER * 4 * 2);
    float*    TX     = (float*)alloc((size_t)(T_CHEB - 1) * NN * F_IN * 4);
    int*      ell_r  = (int*)  alloc((size_t)NN * MD * 4);
    float*    ell_m  = (float*)alloc((size_t)NN * MD * 4);
    float4*   ell_ea = (float4*)alloc((size_t)NN * MD * 16);
    _Float16* v0     = (_Float16*)alloc((size_t)NN * H * 2);
    _Float16* v1     = (_Float16*)alloc((size_t)NN * H * 2);
    float*    hA     = (float*)alloc((size_t)NN * H * 4);
    float*    hB     = (float*)alloc((size_t)NN * H * 4);
    (void)ws_size; (void)n_in; (void)in_sizes; (void)out_size;

    const int B = 256;
    auto G = [](long n, int b) { return (int)((n + b - 1) / b); };

    hipMemsetAsync(deg, 0, ctl_bytes, stream);
    k_front<<<360, B, 0, stream>>>(enc_w, enc_b, w1, b1, w2, b2, root,
                                   row, col, eattr, Mfrag, deg, cnt, ell_r, ell_m, ell_ea);

    float* T1 = (float*)TX;
    float* T2 = T1 + (size_t)NN * F_IN;
    float* T3 = T2 + (size_t)NN * F_IN;
    float* T4 = T3 + (size_t)NN * F_IN;
    k_cheb_step<<<G((long)NN * 4, B), B, 0, stream>>>(cnt, ell_r, ell_m, deg, x,  nullptr, T1, 1.f);
    k_cheb_step<<<G((long)NN * 4, B), B, 0, stream>>>(cnt, ell_r, ell_m, deg, T1, x,       T2, 2.f);
    k_cheb_step<<<G((long)NN * 4, B), B, 0, stream>>>(cnt, ell_r, ell_m, deg, T2, T1,      T3, 2.f);
    k_cheb4_out<<<G(NN, 64), B, 0, stream>>>(cnt, ell_r, ell_m, deg, x, T1, T2, T3, T4,
                                             cheb_w, cheb_b, v0);

    // layers: v ping-pong (f16), h ping-pong (f32, residual)
    _Float16* vbuf[2] = { v0, v1 };
    float*    hbuf[2] = { hA, hB };
    for (int li = 0; li < L_LAYERS; ++li) {
        int isLast = (li == L_LAYERS - 1);
        const _Float16* vcur = vbuf[li & 1];
        _Float16*       vnx  = vbuf[(li + 1) & 1];
        const float*    hres = (li > 0) ? hbuf[(li + 1) & 1] : nullptr;  // h_{li-1}
        float*          hnx  = hbuf[li & 1];                              // h_li
        // epilogue LN params: next layer's (i+1) for i<9, params[0] for i=9
        const float* elg = isLast ? ln_g : ln_g + (li + 1) * H;
        const float* elb = isLast ? ln_b : ln_b + (li + 1) * H;
        k_layer<<<NBT2, 128, 0, stream>>>(
            vcur, hres, cnt, ell_r, ell_ea,
            Mfrag + (size_t)li * FRAG_PER_LAYER * 4,
            conv_b + li * H, elg, elb, lin_w, lin_b,
            hnx, vnx, (float*)d_out, isLast);
    }
}

// Round 12
// 164.561 us; speedup vs baseline: 11.2264x; 1.0262x over previous
//
#include <hip/hip_runtime.h>

#define NN 5000
#define EE 10000
#define F_IN 16
#define F_EDGE 4
#define H 96
#define EHD 16
#define HID3 32
#define T_CHEB 5
#define L_LAYERS 10
#define C_OUT 3
#define LN_EPSF 1e-5f
#define KW 576    // stacked K: 4 attr mats + const mat + root
#define MD 32     // ELL max in-degree (dataset max ~13)
#define BM2 16    // rows per layer block
#define NBT2 313  // ceil(5000/16)
#define KC_N 36   // K chunks of 16
#define FRAG_PER_LAYER (6 * KC_N * 64)   // half4 units per layer (nt,kc,lane)

typedef float float4v __attribute__((ext_vector_type(4)));
typedef _Float16 half2v __attribute__((ext_vector_type(2)));
typedef _Float16 half4v __attribute__((ext_vector_type(4)));
typedef _Float16 half8v __attribute__((ext_vector_type(8)));

// Proven on this hardware in R9/R10 (compiled host+device, ran, absmax 1.56e-2):
#define MFMA16(a, b, c) __builtin_amdgcn_mfma_f32_16x16x16f16((a), (b), (c), 0, 0, 0)

// ========= front-end: M_stack (576x96) to f16 B-fragments + ELL setup =========
// B-frag (16x16x16): lane = n15 + 16*g holds B[k = kc*16 + 4g + e][col = nt*16 + n15]
// Linear half index: (((i*6 + nt)*36 + kc)*64 + lane)*4 + e
__global__ void k_front(const float* __restrict__ enc_w, const float* __restrict__ enc_b,
                        const float* __restrict__ w1, const float* __restrict__ b1,
                        const float* __restrict__ w2, const float* __restrict__ b2,
                        const float* __restrict__ root,
                        const int* __restrict__ row, const int* __restrict__ col,
                        const float* __restrict__ eattr,
                        _Float16* __restrict__ Mf, float* __restrict__ deg,
                        int* __restrict__ cnt, int* __restrict__ ell_r,
                        float* __restrict__ ell_m, float4* __restrict__ ell_ea) {
    const int tid = blockIdx.x * blockDim.x + threadIdx.x;
    const int NTH = gridDim.x * blockDim.x;
    for (int idx = tid; idx < L_LAYERS * H * H; idx += NTH) {
        int i = idx / (H * H);
        int m = idx % (H * H);      // m = h*96 + o   (h: inner K row, o: output col)
        int h = m / H, o = m % H;
        const float* w2i = w2 + (size_t)i * HID3 * H * H;
        const float* w1i = w1 + i * EHD * HID3;
        float hcol[HID3];
        #pragma unroll
        for (int k2 = 0; k2 < HID3; ++k2) hcol[k2] = w2i[(size_t)k2 * H * H + m];
        float tcol[EHD];
        #pragma unroll
        for (int ke = 0; ke < EHD; ++ke) {
            float s = 0.f;
            #pragma unroll
            for (int k2 = 0; k2 < HID3; ++k2) s += w1i[ke * HID3 + k2] * hcol[k2];
            tcol[ke] = s;
        }
        float vals[6];
        #pragma unroll
        for (int f = 0; f < F_EDGE; ++f) {
            float s = 0.f;
            #pragma unroll
            for (int ke = 0; ke < EHD; ++ke) s += enc_w[f * EHD + ke] * tcol[ke];
            vals[f] = s;
        }
        float c = b2[(size_t)i * H * H + m];
        #pragma unroll
        for (int ke = 0; ke < EHD; ++ke) c += enc_b[ke] * tcol[ke];
        #pragma unroll
        for (int k2 = 0; k2 < HID3; ++k2) c += b1[i * HID3 + k2] * hcol[k2];
        vals[4] = c;
        vals[5] = root[(size_t)i * H * H + m];
        int nt = o >> 4, n15 = o & 15;
        #pragma unroll
        for (int f = 0; f < 6; ++f) {
            int K = f * 96 + h;                      // stacked K index
            int kc = K >> 4, g2 = (K & 15) >> 2, e2 = K & 3;
            int lane = n15 + 16 * g2;
            Mf[((((size_t)i * 6 + nt) * KC_N + kc) * 64 + lane) * 4 + e2] = (_Float16)vals[f];
        }
    }
    for (int e = tid; e < EE; e += NTH) {
        int r = row[e], c = col[e];
        float4 ea = *(const float4*)(eattr + e * F_EDGE);
        float m = (ea.x == 0.f && r != c) ? 1.f : 0.f;
        if (m != 0.f) atomicAdd(&deg[r], 1.f);   // integer-valued: exact
        int slot = atomicAdd(&cnt[c], 1);
        int p = c * MD + slot;
        ell_r[p] = r;
        ell_m[p] = m;
        ell_ea[p] = ea;
    }
}

// ====== Cheb A: T1 and T2 in one pass (neighbor T1 recomputed on the fly) ======
__global__ void k_chebA(const int* __restrict__ cnt, const int* __restrict__ ell_r,
                        const float* __restrict__ ell_m, const float* __restrict__ deg,
                        const float* __restrict__ x,
                        float* __restrict__ T1, float* __restrict__ T2) {
    int t = blockIdx.x * blockDim.x + threadIdx.x;
    if (t >= NN * 4) return;
    int c = t >> 2, q = t & 3;
    float dc = deg[c];
    float dinvC = dc > 0.f ? rsqrtf(dc) : 0.f;
    int nc = cnt[c];
    const int* rp = ell_r + c * MD;
    const float* mp = ell_m + c * MD;
    float4 acc1 = make_float4(0.f, 0.f, 0.f, 0.f);
    float4 acc2 = make_float4(0.f, 0.f, 0.f, 0.f);
    for (int p = 0; p < nc; ++p) {
        if (mp[p] == 0.f) continue;
        int r = rp[p];
        float dinvR = rsqrtf(deg[r]);
        float4 xr = *(const float4*)(x + (size_t)r * F_IN + q * 4);
        acc1.x = fmaf(dinvR, xr.x, acc1.x); acc1.y = fmaf(dinvR, xr.y, acc1.y);
        acc1.z = fmaf(dinvR, xr.z, acc1.z); acc1.w = fmaf(dinvR, xr.w, acc1.w);
        // T1 on the fly for r
        float4 a = make_float4(0.f, 0.f, 0.f, 0.f);
        int nr = cnt[r];
        const int* rp2 = ell_r + r * MD;
        const float* mp2 = ell_m + r * MD;
        for (int p2 = 0; p2 < nr; ++p2) {
            if (mp2[p2] == 0.f) continue;
            int r2 = rp2[p2];
            float w2v = rsqrtf(deg[r2]);
            float4 x2 = *(const float4*)(x + (size_t)r2 * F_IN + q * 4);
            a.x = fmaf(w2v, x2.x, a.x); a.y = fmaf(w2v, x2.y, a.y);
            a.z = fmaf(w2v, x2.z, a.z); a.w = fmaf(w2v, x2.w, a.w);
        }
        float f1 = -dinvR;
        acc2.x = fmaf(dinvR, f1 * a.x, acc2.x); acc2.y = fmaf(dinvR, f1 * a.y, acc2.y);
        acc2.z = fmaf(dinvR, f1 * a.z, acc2.z); acc2.w = fmaf(dinvR, f1 * a.w, acc2.w);
    }
    float4 xc = *(const float4*)(x + (size_t)c * F_IN + q * 4);
    float f = -dinvC;
    *(float4*)(T1 + (size_t)c * F_IN + q * 4) =
        make_float4(f * acc1.x, f * acc1.y, f * acc1.z, f * acc1.w);
    float f2 = -2.f * dinvC;
    *(float4*)(T2 + (size_t)c * F_IN + q * 4) =
        make_float4(f2 * acc2.x - xc.x, f2 * acc2.y - xc.y,
                    f2 * acc2.z - xc.z, f2 * acc2.w - xc.w);
}

// ====== Cheb B: T3 (own, LDS), T4 (own, neighbor-T3 on the fly), cheb_out -> v0 f16 ======
__global__ __launch_bounds__(256) void k_chebB(
        const int* __restrict__ cnt, const int* __restrict__ ell_r,
        const float* __restrict__ ell_m, const float* __restrict__ deg,
        const float* __restrict__ x, const float* __restrict__ T1,
        const float* __restrict__ T2, const float* __restrict__ cheb_w,
        const float* __restrict__ cheb_b, _Float16* __restrict__ vout) {
    __shared__ float wlds[T_CHEB * F_IN][H];   // 30 KB
    __shared__ float t34[2][64][F_IN];         // 8 KB
    const int n0 = blockIdx.x * 64;
    const int t = threadIdx.x;
    for (int i = t; i < T_CHEB * F_IN * H / 4; i += 256)
        ((float4*)wlds)[i] = ((const float4*)cheb_w)[i];
    {
        int c = n0 + (t >> 2), q = t & 3;
        if (c < NN) {
            float dc = deg[c];
            float dinvC = dc > 0.f ? rsqrtf(dc) : 0.f;
            int nc = cnt[c];
            const int* rp = ell_r + c * MD;
            const float* mp = ell_m + c * MD;
            float4 a3 = make_float4(0.f, 0.f, 0.f, 0.f);
            float4 a4 = make_float4(0.f, 0.f, 0.f, 0.f);
            for (int p = 0; p < nc; ++p) {
                if (mp[p] == 0.f) continue;
                int r = rp[p];
                float dinvR = rsqrtf(deg[r]);
                float4 t2r = *(const float4*)(T2 + (size_t)r * F_IN + q * 4);
                a3.x = fmaf(dinvR, t2r.x, a3.x); a3.y = fmaf(dinvR, t2r.y, a3.y);
                a3.z = fmaf(dinvR, t2r.z, a3.z); a3.w = fmaf(dinvR, t2r.w, a3.w);
                float4 b = make_float4(0.f, 0.f, 0.f, 0.f);
                int nr = cnt[r];
                const int* rp2 = ell_r + r * MD;
                const float* mp2 = ell_m + r * MD;
                for (int p2 = 0; p2 < nr; ++p2) {
                    if (mp2[p2] == 0.f) continue;
                    int r2 = rp2[p2];
                    float w2v = rsqrtf(deg[r2]);
                    float4 t2b = *(const float4*)(T2 + (size_t)r2 * F_IN + q * 4);
                    b.x = fmaf(w2v, t2b.x, b.x); b.y = fmaf(w2v, t2b.y, b.y);
                    b.z = fmaf(w2v, t2b.z, b.z); b.w = fmaf(w2v, t2b.w, b.w);
                }
                float fr = -2.f * dinvR;
                float4 t1r = *(const float4*)(T1 + (size_t)r * F_IN + q * 4);
                float4 t3r = make_float4(fr * b.x - t1r.x, fr * b.y - t1r.y,
                                         fr * b.z - t1r.z, fr * b.w - t1r.w);
                a4.x = fmaf(dinvR, t3r.x, a4.x); a4.y = fmaf(dinvR, t3r.y, a4.y);
                a4.z = fmaf(dinvR, t3r.z, a4.z); a4.w = fmaf(dinvR, t3r.w, a4.w);
            }
            float f3 = -2.f * dinvC;
            float4 t1c = *(const float4*)(T1 + (size_t)c * F_IN + q * 4);
            float4 t2c = *(const float4*)(T2 + (size_t)c * F_IN + q * 4);
            int lr = t >> 2;
            *(float4*)&t34[0][lr][q * 4] =
                make_float4(f3 * a3.x - t1c.x, f3 * a3.y - t1c.y,
                            f3 * a3.z - t1c.z, f3 * a3.w - t1c.w);
            *(float4*)&t34[1][lr][q * 4] =
                make_float4(f3 * a4.x - t2c.x, f3 * a4.y - t2c.y,
                            f3 * a4.z - t2c.z, f3 * a4.w - t2c.w);
        }
    }
    __syncthreads();
    {
        int lr = t >> 2, n = n0 + lr, cseg = t & 3;
        if (n >= NN) return;
        float txv[T_CHEB * F_IN];
        #pragma unroll
        for (int q = 0; q < 4; ++q) {
            *(float4*)(txv + q * 4)      = *(const float4*)(x  + (size_t)n * F_IN + q * 4);
            *(float4*)(txv + 16 + q * 4) = *(const float4*)(T1 + (size_t)n * F_IN + q * 4);
            *(float4*)(txv + 32 + q * 4) = *(const float4*)(T2 + (size_t)n * F_IN + q * 4);
            *(float4*)(txv + 48 + q * 4) = *(const float4*)&t34[0][lr][q * 4];
            *(float4*)(txv + 64 + q * 4) = *(const float4*)&t34[1][lr][q * 4];
        }
        _Float16* vr = vout + (size_t)n * H + cseg * 24;
        #pragma unroll 4
        for (int c = 0; c < 24; ++c) {
            int o = cseg * 24 + c;
            float s = cheb_b[o];
            #pragma unroll
            for (int kf = 0; kf < T_CHEB * F_IN; ++kf)
                s = fmaf(txv[kf], wlds[kf][o], s);
            vr[c] = (_Float16)s;
        }
    }
}

// ====== per-layer: z-aggregate + 4-way split-K MFMA (16x96, K=576) + LN epilogue ======
// grid 313 x 512 (8 waves). wave: nt-half = wid&1, K-quarter = wid>>1 (9 kc of 16).
__global__ __launch_bounds__(512) void k_layer(
        const _Float16* __restrict__ vcur, const float* __restrict__ hres,
        const int* __restrict__ cnt, const int* __restrict__ ell_r,
        const float4* __restrict__ ell_ea, const _Float16* __restrict__ MfL,
        const float* __restrict__ cb, const float* __restrict__ lg,
        const float* __restrict__ lb, const float* __restrict__ lin_w,
        const float* __restrict__ lin_b,
        float* __restrict__ hnext, _Float16* __restrict__ vnext,
        float* __restrict__ outp, int isLast) {
    __shared__ __align__(16) _Float16 zs[BM2][584];   // 18.7 KB
    __shared__ float hop[4][BM2][100];                // 25.6 KB
    const int n0 = blockIdx.x * BM2;
    const int t = threadIdx.x;

    // ---- phase 1: build z rows (16 lanes/row, first 256 threads) ----
    if (t < 256) {
        int r = t >> 4, lane16 = t & 15;
        int gn = n0 + r, c0 = lane16 * 6;
        float accf[5][6] = {};
        half2v self0 = (half2v)(_Float16)0.f, self1 = self0, self2 = self0;
        if (gn < NN) {
            const _Float16* sv = vcur + (size_t)gn * H + c0;
            self0 = *(const half2v*)(sv + 0);
            self1 = *(const half2v*)(sv + 2);
            self2 = *(const half2v*)(sv + 4);
            int nc = cnt[gn];
            const int* rp = ell_r + gn * MD;
            const float4* eap = ell_ea + gn * MD;
            for (int p = 0; p < nc; ++p) {
                int r2 = rp[p];
                float4 ea = eap[p];
                const _Float16* vv = vcur + (size_t)r2 * H + c0;
                half2v v0 = *(const half2v*)(vv + 0);
                half2v v1 = *(const half2v*)(vv + 2);
                half2v v2 = *(const half2v*)(vv + 4);
                float vf[6] = {(float)v0[0], (float)v0[1], (float)v1[0],
                               (float)v1[1], (float)v2[0], (float)v2[1]};
                const float cf[4] = {ea.x, ea.y, ea.z, ea.w};
                #pragma unroll
                for (int f = 0; f < 4; ++f)
                    #pragma unroll
                    for (int j = 0; j < 6; ++j)
                        accf[f][j] = fmaf(cf[f], vf[j], accf[f][j]);
                #pragma unroll
                for (int j = 0; j < 6; ++j) accf[4][j] += vf[j];
            }
        }
        #pragma unroll
        for (int f = 0; f < 5; ++f) {
            _Float16* zp = &zs[r][f * 96 + c0];
            *(half2v*)(zp + 0) = half2v{(_Float16)accf[f][0], (_Float16)accf[f][1]};
            *(half2v*)(zp + 2) = half2v{(_Float16)accf[f][2], (_Float16)accf[f][3]};
            *(half2v*)(zp + 4) = half2v{(_Float16)accf[f][4], (_Float16)accf[f][5]};
        }
        _Float16* zp = &zs[r][480 + c0];
        *(half2v*)(zp + 0) = self0;
        *(half2v*)(zp + 2) = self1;
        *(half2v*)(zp + 4) = self2;
    }
    __syncthreads();

    // ---- phase 2: MFMA, split-K (4 segments) x nt-half across 8 waves ----
    {
        const int wid = t >> 6, l = t & 63;
        const int n15 = l & 15, g = l >> 4;
        const int ntBase = (wid & 1) * 3;
        const int kSeg = wid >> 1;            // 0..3
        const int kcBase = kSeg * 9;          // 9 kc16 chunks each
        const half4v* Mf4 = (const half4v*)MfL;
        half4v af[9];
        #pragma unroll
        for (int kk = 0; kk < 9; ++kk)
            af[kk] = *(const half4v*)&zs[n15][(kcBase + kk) * 16 + 4 * g];
        float4v acc3[3] = {};
        #pragma unroll
        for (int j = 0; j < 3; ++j) {
            int nt = ntBase + j;
            const half4v* Bp = Mf4 + ((size_t)nt * KC_N + kcBase) * 64 + l;
            #pragma unroll
            for (int kk = 0; kk < 9; ++kk)
                acc3[j] = MFMA16(af[kk], Bp[kk * 64], acc3[j]);
        }
        #pragma unroll
        for (int j = 0; j < 3; ++j) {
            int cc = (ntBase + j) * 16 + n15;
            #pragma unroll
            for (int e = 0; e < 4; ++e)
                hop[kSeg][4 * g + e][cc] = acc3[j][e];
        }
    }
    __syncthreads();

    // ---- phase 3: combine partials + residual + LN + ReLU (or linear head) ----
    if (t < 256) {
        int r = t >> 4, lane16 = t & 15;
        int gn = n0 + r, c0 = lane16 * 6;
        float hv[6];
        #pragma unroll
        for (int j = 0; j < 6; ++j)
            hv[j] = hop[0][r][c0 + j] + hop[1][r][c0 + j]
                  + hop[2][r][c0 + j] + hop[3][r][c0 + j] + cb[c0 + j];
        if (hres && gn < NN) {
            const float* rp = hres + (size_t)gn * H + c0;
            #pragma unroll
            for (int j = 0; j < 6; j += 2) {
                float2 rv = *(const float2*)(rp + j);
                hv[j] += rv.x; hv[j + 1] += rv.y;
            }
        }
        if (!isLast && gn < NN) {
            float* hp = hnext + (size_t)gn * H + c0;
            #pragma unroll
            for (int j = 0; j < 6; j += 2)
                *(float2*)(hp + j) = make_float2(hv[j], hv[j + 1]);
        }
        float s = 0.f;
        #pragma unroll
        for (int j = 0; j < 6; ++j) s += hv[j];
        s += __shfl_xor(s, 1); s += __shfl_xor(s, 2);
        s += __shfl_xor(s, 4); s += __shfl_xor(s, 8);
        float mu = s * (1.0f / H);
        float vvr = 0.f;
        #pragma unroll
        for (int j = 0; j < 6; ++j) { float d = hv[j] - mu; vvr += d * d; }
        vvr += __shfl_xor(vvr, 1); vvr += __shfl_xor(vvr, 2);
        vvr += __shfl_xor(vvr, 4); vvr += __shfl_xor(vvr, 8);
        float is = rsqrtf(vvr * (1.0f / H) + LN_EPSF);
        const float* gp = lg + c0;
        const float* bp = lb + c0;
        float yv[6];
        #pragma unroll
        for (int j = 0; j < 6; ++j)
            yv[j] = fmaxf(fmaf((hv[j] - mu) * is, gp[j], bp[j]), 0.f);
        if (!isLast) {
            if (gn < NN) {
                _Float16* vp = vnext + (size_t)gn * H + c0;
                *(half2v*)(vp + 0) = half2v{(_Float16)yv[0], (_Float16)yv[1]};
                *(half2v*)(vp + 2) = half2v{(_Float16)yv[2], (_Float16)yv[3]};
                *(half2v*)(vp + 4) = half2v{(_Float16)yv[4], (_Float16)yv[5]};
            }
        } else {
            float a0 = 0.f, a1 = 0.f, a2 = 0.f;
            #pragma unroll
            for (int j = 0; j < 6; ++j) {
                int oo = c0 + j;
                a0 = fmaf(yv[j], lin_w[oo * C_OUT + 0], a0);
                a1 = fmaf(yv[j], lin_w[oo * C_OUT + 1], a1);
                a2 = fmaf(yv[j], lin_w[oo * C_OUT + 2], a2);
            }
            a0 += __shfl_xor(a0, 1); a0 += __shfl_xor(a0, 2);
            a0 += __shfl_xor(a0, 4); a0 += __shfl_xor(a0, 8);
            a1 += __shfl_xor(a1, 1); a1 += __shfl_xor(a1, 2);
            a1 += __shfl_xor(a1, 4); a1 += __shfl_xor(a1, 8);
            a2 += __shfl_xor(a2, 1); a2 += __shfl_xor(a2, 2);
            a2 += __shfl_xor(a2, 4); a2 += __shfl_xor(a2, 8);
            if (lane16 == 0 && gn < NN) {
                outp[gn * C_OUT + 0] = a0 + lin_b[0];
                outp[gn * C_OUT + 1] = a1 + lin_b[1];
                outp[gn * C_OUT + 2] = a2 + lin_b[2];
            }
        }
    }
}

extern "C" void kernel_launch(void* const* d_in, const int* in_sizes, int n_in,
                              void* d_out, int out_size, void* d_ws, size_t ws_size,
                              hipStream_t stream) {
    const float* x      = (const float*)d_in[0];
    const int*   row    = (const int*)d_in[1];
    const int*   col    = (const int*)d_in[1] + EE;
    const float* eattr  = (const float*)d_in[2];
    const float* cheb_w = (const float*)d_in[3];
    const float* cheb_b = (const float*)d_in[4];
    const float* enc_w  = (const float*)d_in[5];
    const float* enc_b  = (const float*)d_in[6];
    const float* w1     = (const float*)d_in[7];
    const float* b1     = (const float*)d_in[8];
    const float* w2     = (const float*)d_in[9];
    const float* b2     = (const float*)d_in[10];
    const float* root   = (const float*)d_in[11];
    const float* conv_b = (const float*)d_in[12];
    const float* ln_g   = (const float*)d_in[13];
    const float* ln_b   = (const float*)d_in[14];
    const float* lin_w  = (const float*)d_in[15];
    const float* lin_b  = (const float*)d_in[16];

    char* base = (char*)d_ws;
    size_t off = 0;
    auto alloc = [&](size_t nbytes) {
        char* p = base + off;
        off += (nbytes + 255) / 256 * 256;
        return p;
    };
    float*    deg    = (float*)alloc(NN * 4);
    int*      cnt    = (int*)  alloc(NN * 4);
    size_t    ctl_bytes = off;
    _Float16* Mfrag  = (_Float16*)alloc((size_t)L_LAYERS * FRAG_PER_LAYER * 4 * 2);
    float*    T1     = (float*)alloc((size_t)NN * F_IN * 4);
    float*    T2     = (float*)alloc((size_t)NN * F_IN * 4);
    int*      ell_r  = (int*)  alloc((size_t)NN * MD * 4);
    float*    ell_m  = (float*)alloc((size_t)NN * MD * 4);
    float4*   ell_ea = (float4*)alloc((size_t)NN * MD * 16);
    _Float16* v0     = (_Float16*)alloc((size_t)NN * H * 2);
    _Float16* v1     = (_Float16*)alloc((size_t)NN * H * 2);
    float*    hA     = (float*)alloc((size_t)NN * H * 4);
    float*    hB     = (float*)alloc((size_t)NN * H * 4);
    (void)ws_size; (void)n_in; (void)in_sizes; (void)out_size;

    const int B = 256;
    auto G = [](long n, int b) { return (int)((n + b - 1) / b); };

    (void)hipMemsetAsync(deg, 0, ctl_bytes, stream);
    k_front<<<360, B, 0, stream>>>(enc_w, enc_b, w1, b1, w2, b2, root,
                                   row, col, eattr, Mfrag, deg, cnt, ell_r, ell_m, ell_ea);
    k_chebA<<<G((long)NN * 4, B), B, 0, stream>>>(cnt, ell_r, ell_m, deg, x, T1, T2);
    k_chebB<<<G(NN, 64), B, 0, stream>>>(cnt, ell_r, ell_m, deg, x, T1, T2,
                                         cheb_w, cheb_b, v0);

    _Float16* vbuf[2] = { v0, v1 };
    float*    hbuf[2] = { hA, hB };
    for (int li = 0; li < L_LAYERS; ++li) {
        int isLast = (li == L_LAYERS - 1);
        const _Float16* vcur = vbuf[li & 1];
        _Float16*       vnx  = vbuf[(li + 1) & 1];
        const float*    hres = (li > 0) ? hbuf[(li + 1) & 1] : nullptr;
        float*          hnx  = hbuf[li & 1];
        const float* elg = isLast ? ln_g : ln_g + (li + 1) * H;
        const float* elb = isLast ? ln_b : ln_b + (li + 1) * H;
        k_layer<<<NBT2, 512, 0, stream>>>(
            vcur, hres, cnt, ell_r, ell_ea,
            Mfrag + (size_t)li * FRAG_PER_LAYER * 4,
            conv_b + li * H, elg, elb, lin_w, lin_b,
            hnx, vnx, (float*)d_out, isLast);
    }
}